// Round 10
// baseline (409.003 us; speedup 1.0000x reference)
//
#include <hip/hip_runtime.h>
#include <hip/hip_bf16.h>
#include <math.h>

typedef unsigned short ushort_t;
typedef __attribute__((ext_vector_type(8))) short short8;
typedef __attribute__((ext_vector_type(4))) float f32x4;
typedef __attribute__((ext_vector_type(4))) unsigned short u16x4;

static __device__ __forceinline__ float b2f(ushort_t u) {
    union { unsigned int i; float f; } v; v.i = ((unsigned int)u) << 16; return v.f;
}
static __device__ __forceinline__ ushort_t f2b(float f) {
    unsigned int x = __float_as_uint(f);
    unsigned int r = (x + 0x7fffu + ((x >> 16) & 1u)) >> 16;
    return (ushort_t)r;
}

// ---------------- fp32 -> bf16 convert ----------------

__global__ void conv_kernel(const float* __restrict__ src, ushort_t* __restrict__ dst, int n4) {
    for (int i = blockIdx.x * blockDim.x + threadIdx.x; i < n4; i += gridDim.x * blockDim.x) {
        float4 v = *(const float4*)(src + i * 4);
        u16x4 o = { f2b(v.x), f2b(v.y), f2b(v.z), f2b(v.w) };
        *(u16x4*)(dst + i * 4) = o;
    }
}

// folded attention rows: wa[col][k] = sum_c W[(h*Cd+c)*K + k] * a[h*Cd+c]
template<int K, int Cd>
__global__ void build_wa(const float* __restrict__ W, const float* __restrict__ as,
                         const float* __restrict__ ad, ushort_t* __restrict__ Bext, int rowoff) {
    int tid = blockIdx.x * blockDim.x + threadIdx.x;
    if (tid >= 16 * K) return;
    int col = tid / K, k = tid - col * K;
    const float* a = (col < 8) ? as : ad;
    int h = col & 7;
    float s = 0.f;
    #pragma unroll 4
    for (int c = 0; c < Cd; ++c)
        s += W[(size_t)(h * Cd + c) * K + k] * a[h * Cd + c];
    Bext[(size_t)(rowoff + col) * K + k] = f2b(s);
}

// pad rows: als1/als2 row n = -1e30 (sentinel -> zero weight), h1b/h2b row n = 0
__global__ void pad_row_kernel(float* als1, float* als2, ushort_t* h1b, ushort_t* h2b, int n) {
    int t = threadIdx.x;
    if (t < 8) { als1[(size_t)n * 8 + t] = -1e30f; als2[(size_t)n * 8 + t] = -1e30f; }
    if (t < 256) h1b[(size_t)n * 256 + t] = 0;
    if (t < 320) h2b[(size_t)n * 320 + t] = 0;
}

// ---------------- CSR build (rows padded to multiples of 8) ----------------

__global__ void count_kernel(const int* __restrict__ ei, int E, int n, int* __restrict__ deg) {
    int e = blockIdx.x * blockDim.x + threadIdx.x;
    int Etot = E + n;
    if (e >= Etot) return;
    int dst = (e < E) ? ei[E + e] : (e - E);
    atomicAdd(&deg[dst], 1);
}

__global__ void scan_kernel(const int* __restrict__ deg, int* __restrict__ rowptr,
                            int* __restrict__ cursor, int n) {
    __shared__ int wsum[16];
    int t = threadIdx.x;
    int lane = t & 63, wid = t >> 6;
    int carry = 0;
    for (int base = 0; base < n; base += 1024) {
        int i = base + t;
        int v = (i < n) ? ((deg[i] + 7) & ~7) : 0;   // padded degree
        int val = v;
        #pragma unroll
        for (int off = 1; off < 64; off <<= 1) {
            int nv = __shfl_up(val, off);
            if (lane >= off) val += nv;
        }
        if (lane == 63) wsum[wid] = val;
        __syncthreads();
        int wpre = 0, tot = 0;
        #pragma unroll
        for (int w = 0; w < 16; ++w) {
            int s = wsum[w];
            if (w < wid) wpre += s;
            tot += s;
        }
        int excl = carry + wpre + val - v;
        if (i < n) { rowptr[i] = excl; cursor[i] = excl; }
        carry += tot;
        __syncthreads();
    }
    if (t == 0) rowptr[n] = carry;
}

__global__ void scatter_kernel(const int* __restrict__ ei, int E, int n,
                               int* __restrict__ cursor, int* __restrict__ ssrc) {
    int e = blockIdx.x * blockDim.x + threadIdx.x;
    int Etot = E + n;
    if (e >= Etot) return;
    int src, dst;
    if (e < E) { src = ei[e]; dst = ei[E + e]; }
    else       { src = e - E; dst = e - E; }
    int pos = atomicAdd(&cursor[dst], 1);
    ssrc[pos] = src;
}

__global__ void pad_fill_kernel(const int* __restrict__ rowptr, const int* __restrict__ cursor,
                                int* __restrict__ ssrc, int n) {
    int i = blockIdx.x * blockDim.x + threadIdx.x;
    if (i >= n) return;
    int p = cursor[i], e = rowptr[i + 1];
    for (; p < e; ++p) ssrc[p] = n;   // sentinel
}

// ---------------- bf16 MFMA NT GEMM + fused attention logits ----------------

template<int NFRAG, int K>
__global__ __launch_bounds__(512) void gemm_lds_al(const ushort_t* __restrict__ A,
                                                   const ushort_t* __restrict__ B,
                                                   ushort_t* __restrict__ C,
                                                   float* __restrict__ als,
                                                   float* __restrict__ ald, int M) {
    constexpr int N = NFRAG * 16;
    constexpr int NOUT = (NFRAG - 1) * 16;
    constexpr int RS = 40;                 // LDS row stride in elems
    constexpr int NK = K / 32;
    __shared__ ushort_t Bs[2][N * RS];
    const int t = threadIdx.x;
    const int w = t >> 6, l = t & 63;
    const int r0 = blockIdx.x * 128 + w * 16;
    int arow = r0 + (l & 15);
    if (arow >= M) arow = M - 1;
    const int koff = (l >> 4) * 8;
    const ushort_t* ap = A + (size_t)arow * K + koff;

    f32x4 acc[NFRAG];
    #pragma unroll
    for (int i = 0; i < NFRAG; ++i) acc[i] = (f32x4){0.f, 0.f, 0.f, 0.f};

    auto stage = [&](int buf, int k0) {
        #pragma unroll
        for (int c = t; c < N * 4; c += 512) {
            int row = c >> 2, part = (c & 3) << 3;           // part in elems
            *(short8*)&Bs[buf][row * RS + part] =
                *(const short8*)(B + (size_t)row * K + k0 + part);
        }
    };

    stage(0, 0);
    __syncthreads();
    #pragma unroll
    for (int kk = 0; kk < NK; ++kk) {
        int buf = kk & 1;
        if (kk + 1 < NK) stage(buf ^ 1, (kk + 1) * 32);
        short8 a = *(const short8*)(ap + kk * 32);
        #pragma unroll
        for (int nf = 0; nf < NFRAG; ++nf) {
            short8 b = *(const short8*)&Bs[buf][(nf * 16 + (l & 15)) * RS + koff];
            acc[nf] = __builtin_amdgcn_mfma_f32_16x16x32_bf16(a, b, acc[nf], 0, 0, 0);
        }
        __syncthreads();
    }

    const int crow0 = r0 + (l >> 4) * 4;
    #pragma unroll
    for (int nf = 0; nf < NFRAG - 1; ++nf) {
        #pragma unroll
        for (int j = 0; j < 4; ++j) {
            int row = crow0 + j;
            if (row < M) C[(size_t)row * NOUT + nf * 16 + (l & 15)] = f2b(acc[nf][j]);
        }
    }
    {   // attention-logit fragment
        int col = l & 15;
        float* dstp = (col < 8) ? als : ald;
        int h = col & 7;
        #pragma unroll
        for (int j = 0; j < 4; ++j) {
            int row = crow0 + j;
            if (row < M) dstp[(size_t)row * 8 + h] = acc[NFRAG - 1][j];
        }
    }
}

// ---------------- per-edge normalized softmax weights ----------------
// lanes: h = l&7 (head), k = l>>3 (edge slot). Two sweeps: (m,den) then w.
// wts layout: [head][edge] with stride EpM.

__device__ __forceinline__ float lrelu(float e) { return (e > 0.f) ? e : 0.2f * e; }

__global__ void wts_kernel(const float* __restrict__ als, const float* __restrict__ aldv,
                           const int* __restrict__ rowptr, const int* __restrict__ ssrc,
                           float* __restrict__ wts, int EpM, int n) {
    int node = blockIdx.x * 4 + (threadIdx.x >> 6);
    if (node >= n) return;
    int l = threadIdx.x & 63;
    int h = l & 7, k = l >> 3;
    float ald = aldv[node * 8 + h];
    int beg = rowptr[node], end = rowptr[node + 1];
    float m = -1e30f, d = 0.f;
    for (int p = beg; p < end; p += 8) {
        int s = ssrc[p + k];
        float e = lrelu(als[s * 8 + h] + ald);
        if (e > m + 8.f) { d *= __expf(m - e); m = e; }
        d += __expf(e - m);
    }
    // merge across k (lane bits 3..5); exp(m_l - nm)=0 zeroes sentinel-only lanes
    #pragma unroll
    for (int off = 8; off < 64; off <<= 1) {
        float m2 = __shfl_xor(m, off), d2 = __shfl_xor(d, off);
        float nm = fmaxf(m, m2);
        d = d * __expf(m - nm) + d2 * __expf(m2 - nm);
        m = nm;
    }
    float inv = 1.f / d;
    for (int p = beg; p < end; p += 8) {
        int s = ssrc[p + k];
        float e = lrelu(als[s * 8 + h] + ald);
        wts[(size_t)h * EpM + p + k] = __expf(e - m) * inv;
    }
}

// ---------------- layer-1 aggregation: pure weighted gather + bias + ELU ----------------

__global__ void agg1_kernel(const ushort_t* __restrict__ h1, const float* __restrict__ wts,
                            const float* __restrict__ b1,
                            const int* __restrict__ rowptr, const int* __restrict__ ssrc,
                            ushort_t* __restrict__ hout, int EpM, int n) {
    int node = blockIdx.x * 4 + (threadIdx.x >> 6);
    if (node >= n) return;
    int l = threadIdx.x & 63;
    int h = l >> 3;
    const float* wp = wts + (size_t)h * EpM;
    int beg = rowptr[node], end = rowptr[node + 1];
    float a0 = 0.f, a1 = 0.f, a2 = 0.f, a3 = 0.f;
    for (int p = beg; p < end; p += 8) {
        int4 sA = *(const int4*)(ssrc + p);
        int4 sB = *(const int4*)(ssrc + p + 4);
        float4 wA = *(const float4*)(wp + p);
        float4 wB = *(const float4*)(wp + p + 4);
        u16x4 f0 = *(const u16x4*)(h1 + (size_t)sA.x * 256 + l * 4);
        u16x4 f1 = *(const u16x4*)(h1 + (size_t)sA.y * 256 + l * 4);
        u16x4 f2 = *(const u16x4*)(h1 + (size_t)sA.z * 256 + l * 4);
        u16x4 f3 = *(const u16x4*)(h1 + (size_t)sA.w * 256 + l * 4);
        u16x4 f4 = *(const u16x4*)(h1 + (size_t)sB.x * 256 + l * 4);
        u16x4 f5 = *(const u16x4*)(h1 + (size_t)sB.y * 256 + l * 4);
        u16x4 f6 = *(const u16x4*)(h1 + (size_t)sB.z * 256 + l * 4);
        u16x4 f7 = *(const u16x4*)(h1 + (size_t)sB.w * 256 + l * 4);
        a0 += wA.x * b2f(f0.x) + wA.y * b2f(f1.x) + wA.z * b2f(f2.x) + wA.w * b2f(f3.x)
            + wB.x * b2f(f4.x) + wB.y * b2f(f5.x) + wB.z * b2f(f6.x) + wB.w * b2f(f7.x);
        a1 += wA.x * b2f(f0.y) + wA.y * b2f(f1.y) + wA.z * b2f(f2.y) + wA.w * b2f(f3.y)
            + wB.x * b2f(f4.y) + wB.y * b2f(f5.y) + wB.z * b2f(f6.y) + wB.w * b2f(f7.y);
        a2 += wA.x * b2f(f0.z) + wA.y * b2f(f1.z) + wA.z * b2f(f2.z) + wA.w * b2f(f3.z)
            + wB.x * b2f(f4.z) + wB.y * b2f(f5.z) + wB.z * b2f(f6.z) + wB.w * b2f(f7.z);
        a3 += wA.x * b2f(f0.w) + wA.y * b2f(f1.w) + wA.z * b2f(f2.w) + wA.w * b2f(f3.w)
            + wB.x * b2f(f4.w) + wB.y * b2f(f5.w) + wB.z * b2f(f6.w) + wB.w * b2f(f7.w);
    }
    float4 bv = *(const float4*)(b1 + l * 4);
    float v0 = a0 + bv.x, v1 = a1 + bv.y, v2 = a2 + bv.z, v3 = a3 + bv.w;
    u16x4 o;
    o.x = f2b((v0 > 0.f) ? v0 : __expf(v0) - 1.f);
    o.y = f2b((v1 > 0.f) ? v1 : __expf(v1) - 1.f);
    o.z = f2b((v2 > 0.f) ? v2 : __expf(v2) - 1.f);
    o.w = f2b((v3 > 0.f) ? v3 : __expf(v3) - 1.f);
    *(u16x4*)(hout + (size_t)node * 256 + l * 4) = o;
}

// ---------------- layer-2 aggregation: weighted gather + head-mean + log_softmax ----------------

__global__ void agg2_kernel(const ushort_t* __restrict__ h2, const float* __restrict__ wts,
                            const float* __restrict__ b2,
                            const int* __restrict__ rowptr, const int* __restrict__ ssrc,
                            float* __restrict__ out, int EpM, int n) {
    int node = blockIdx.x * 4 + (threadIdx.x >> 6);
    if (node >= n) return;
    int l = threadIdx.x & 63;
    int li = (l < 40) ? l : 0;
    int hd = li / 5;
    int cg = li - hd * 5;
    const float* wp = wts + (size_t)hd * EpM;
    int beg = rowptr[node], end = rowptr[node + 1];
    const ushort_t* base = h2 + hd * 40 + cg * 8;
    float a0 = 0.f, a1 = 0.f, a2 = 0.f, a3 = 0.f, a4 = 0.f, a5 = 0.f, a6 = 0.f, a7 = 0.f;
    for (int p = beg; p < end; p += 8) {
        int4 sA = *(const int4*)(ssrc + p);
        int4 sB = *(const int4*)(ssrc + p + 4);
        float4 wA = *(const float4*)(wp + p);
        float4 wB = *(const float4*)(wp + p + 4);
        short8 f0 = *(const short8*)(base + (size_t)sA.x * 320);
        short8 f1 = *(const short8*)(base + (size_t)sA.y * 320);
        short8 f2 = *(const short8*)(base + (size_t)sA.z * 320);
        short8 f3 = *(const short8*)(base + (size_t)sA.w * 320);
        short8 f4 = *(const short8*)(base + (size_t)sB.x * 320);
        short8 f5 = *(const short8*)(base + (size_t)sB.y * 320);
        short8 f6 = *(const short8*)(base + (size_t)sB.z * 320);
        short8 f7 = *(const short8*)(base + (size_t)sB.w * 320);
        #define ACC(idx, reg) \
            reg += wA.x * b2f((ushort_t)f0[idx]) + wA.y * b2f((ushort_t)f1[idx]) \
                 + wA.z * b2f((ushort_t)f2[idx]) + wA.w * b2f((ushort_t)f3[idx]) \
                 + wB.x * b2f((ushort_t)f4[idx]) + wB.y * b2f((ushort_t)f5[idx]) \
                 + wB.z * b2f((ushort_t)f6[idx]) + wB.w * b2f((ushort_t)f7[idx]);
        ACC(0, a0) ACC(1, a1) ACC(2, a2) ACC(3, a3)
        ACC(4, a4) ACC(5, a5) ACC(6, a6) ACC(7, a7)
        #undef ACC
    }
    float v[8] = {a0, a1, a2, a3, a4, a5, a6, a7};
    #pragma unroll
    for (int j = 0; j < 8; ++j) {
        float s = v[j];
        s += __shfl_down(s, 20);
        s += __shfl_down(s, 10);
        s += __shfl_down(s, 5);
        v[j] = s;
    }
    if (l < 5) {
        float wv[8];
        #pragma unroll
        for (int j = 0; j < 8; ++j) wv[j] = 0.125f * v[j] + b2[l * 8 + j];
        float m8 = wv[0];
        #pragma unroll
        for (int j = 1; j < 8; ++j) m8 = fmaxf(m8, wv[j]);
        float mx = m8;
        #pragma unroll
        for (int k = 0; k < 5; ++k) mx = fmaxf(mx, __shfl(m8, k));
        float se8 = 0.f;
        #pragma unroll
        for (int j = 0; j < 8; ++j) se8 += __expf(wv[j] - mx);
        float se = 0.f;
        #pragma unroll
        for (int k = 0; k < 5; ++k) se += __shfl(se8, k);
        float lse = mx + __logf(se);
        float* op = out + (size_t)node * 40 + l * 8;
        float4 o0 = {wv[0] - lse, wv[1] - lse, wv[2] - lse, wv[3] - lse};
        float4 o1 = {wv[4] - lse, wv[5] - lse, wv[6] - lse, wv[7] - lse};
        *(float4*)op = o0;
        *(float4*)(op + 4) = o1;
    }
}

// ---------------- launch ----------------

extern "C" void kernel_launch(void* const* d_in, const int* in_sizes, int n_in,
                              void* d_out, int out_size, void* d_ws, size_t ws_size,
                              hipStream_t stream) {
    const float* x      = (const float*)d_in[0];
    const int*   ei     = (const int*)d_in[1];
    const float* W1     = (const float*)d_in[2];
    const float* a_src1 = (const float*)d_in[3];
    const float* a_dst1 = (const float*)d_in[4];
    const float* b1     = (const float*)d_in[5];
    const float* W2     = (const float*)d_in[6];
    const float* a_src2 = (const float*)d_in[7];
    const float* a_dst2 = (const float*)d_in[8];
    const float* b2     = (const float*)d_in[9];
    float* out = (float*)d_out;

    const int n    = in_sizes[0] / 128;   // 50000
    const int E    = in_sizes[1] / 2;     // 800000
    const int Etot = E + n;
    const int EpM  = Etot + 7 * n + 16;   // upper bound on padded edge count

    char* w = (char*)d_ws;
    auto take = [&](size_t bytes) {
        char* p = w;
        w += (bytes + 255) & ~(size_t)255;
        return p;
    };
    int*      deg    = (int*)take((size_t)n * 4);
    int*      rowptr = (int*)take((size_t)(n + 1) * 4);
    int*      cursor = (int*)take((size_t)n * 4);
    int*      ssrc   = (int*)take((size_t)EpM * 4);
    ushort_t* xb     = (ushort_t*)take((size_t)n * 128 * 2);
    ushort_t* w1b    = (ushort_t*)take((size_t)272 * 128 * 2);   // 256 W1 rows + 16 wa rows
    ushort_t* w2b    = (ushort_t*)take((size_t)336 * 256 * 2);   // 320 W2 rows + 16 wa rows
    ushort_t* h1b    = (ushort_t*)take((size_t)(n + 1) * 256 * 2);
    ushort_t* helu   = (ushort_t*)take((size_t)n * 256 * 2);
    ushort_t* h2b    = (ushort_t*)take((size_t)(n + 1) * 320 * 2);
    float*    als1   = (float*)take((size_t)(n + 1) * 8 * 4);
    float*    ald1   = (float*)take((size_t)n * 8 * 4);
    float*    als2   = (float*)take((size_t)(n + 1) * 8 * 4);
    float*    ald2   = (float*)take((size_t)n * 8 * 4);
    float*    wts    = (float*)take((size_t)8 * EpM * 4);        // shared between layers

    hipMemsetAsync(deg, 0, (size_t)n * 4, stream);
    pad_row_kernel<<<1, 512, 0, stream>>>(als1, als2, h1b, h2b, n);

    // dtype converts + folded attention rows
    conv_kernel<<<2048, 256, 0, stream>>>(x, xb, n * 128 / 4);
    conv_kernel<<<32, 256, 0, stream>>>(W1, w1b, 256 * 128 / 4);
    conv_kernel<<<80, 256, 0, stream>>>(W2, w2b, 320 * 256 / 4);
    build_wa<128, 32><<<8, 256, 0, stream>>>(W1, a_src1, a_dst1, w1b, 256);
    build_wa<256, 40><<<16, 256, 0, stream>>>(W2, a_src2, a_dst2, w2b, 320);

    // CSR (8-padded rows)
    int eb = (Etot + 255) / 256;
    count_kernel<<<eb, 256, 0, stream>>>(ei, E, n, deg);
    scan_kernel<<<1, 1024, 0, stream>>>(deg, rowptr, cursor, n);
    scatter_kernel<<<eb, 256, 0, stream>>>(ei, E, n, cursor, ssrc);
    pad_fill_kernel<<<(n + 255) / 256, 256, 0, stream>>>(rowptr, cursor, ssrc, n);

    int gb = (n + 127) / 128;
    int nb4 = (n + 3) / 4;

    // layer 1
    gemm_lds_al<17, 128><<<gb, 512, 0, stream>>>(xb, w1b, h1b, als1, ald1, n);
    wts_kernel<<<nb4, 256, 0, stream>>>(als1, ald1, rowptr, ssrc, wts, EpM, n);
    agg1_kernel<<<nb4, 256, 0, stream>>>(h1b, wts, b1, rowptr, ssrc, helu, EpM, n);

    // layer 2
    gemm_lds_al<21, 256><<<gb, 512, 0, stream>>>(helu, w2b, h2b, als2, ald2, n);
    wts_kernel<<<nb4, 256, 0, stream>>>(als2, ald2, rowptr, ssrc, wts, EpM, n);
    agg2_kernel<<<nb4, 256, 0, stream>>>(h2b, wts, b2, rowptr, ssrc, out, EpM, n);
}

// Round 11
// 307.981 us; speedup vs baseline: 1.3280x; 1.3280x over previous
//
#include <hip/hip_runtime.h>
#include <hip/hip_bf16.h>
#include <math.h>

typedef unsigned short ushort_t;
typedef unsigned char uchar_t;
typedef __attribute__((ext_vector_type(8))) short short8;
typedef __attribute__((ext_vector_type(4))) float f32x4;
typedef __attribute__((ext_vector_type(2))) float f32x2;
typedef __attribute__((ext_vector_type(4))) unsigned short u16x4;

static __device__ __forceinline__ float b2f(ushort_t u) {
    union { unsigned int i; float f; } v; v.i = ((unsigned int)u) << 16; return v.f;
}
static __device__ __forceinline__ ushort_t f2b(float f) {
    unsigned int x = __float_as_uint(f);
    unsigned int r = (x + 0x7fffu + ((x >> 16) & 1u)) >> 16;
    return (ushort_t)r;
}
static __device__ __forceinline__ uchar_t f2e4m3(float f) {
    int r = __builtin_amdgcn_cvt_pk_fp8_f32(f, f, 0, false);
    return (uchar_t)(r & 0xff);
}

// ---------------- fp32 -> bf16 convert ----------------

__global__ void conv_kernel(const float* __restrict__ src, ushort_t* __restrict__ dst, int n4) {
    for (int i = blockIdx.x * blockDim.x + threadIdx.x; i < n4; i += gridDim.x * blockDim.x) {
        float4 v = *(const float4*)(src + i * 4);
        u16x4 o = { f2b(v.x), f2b(v.y), f2b(v.z), f2b(v.w) };
        *(u16x4*)(dst + i * 4) = o;
    }
}

// folded attention rows: wa[col][k] = sum_c W[(h*Cd+c)*K + k] * a[h*Cd+c]
template<int K, int Cd>
__global__ void build_wa(const float* __restrict__ W, const float* __restrict__ as,
                         const float* __restrict__ ad, ushort_t* __restrict__ Bext, int rowoff) {
    int tid = blockIdx.x * blockDim.x + threadIdx.x;
    if (tid >= 16 * K) return;
    int col = tid / K, k = tid - col * K;
    const float* a = (col < 8) ? as : ad;
    int h = col & 7;
    float s = 0.f;
    #pragma unroll 4
    for (int c = 0; c < Cd; ++c)
        s += W[(size_t)(h * Cd + c) * K + k] * a[h * Cd + c];
    Bext[(size_t)(rowoff + col) * K + k] = f2b(s);
}

// pad rows: als1/als2 row n = -1e30 (sentinel -> zero weight), h1/h2 fp8 row n = 0
__global__ void pad_row_kernel(float* als1, float* als2, uchar_t* h1f8, uchar_t* h2f8, int n) {
    int t = threadIdx.x;
    if (t < 8) { als1[(size_t)n * 8 + t] = -1e30f; als2[(size_t)n * 8 + t] = -1e30f; }
    if (t < 256) h1f8[(size_t)n * 256 + t] = 0;
    if (t < 320) h2f8[(size_t)n * 320 + t] = 0;
}

// ---------------- CSR build (rows padded to multiples of 8) ----------------

__global__ void count_kernel(const int* __restrict__ ei, int E, int n, int* __restrict__ deg) {
    int e = blockIdx.x * blockDim.x + threadIdx.x;
    int Etot = E + n;
    if (e >= Etot) return;
    int dst = (e < E) ? ei[E + e] : (e - E);
    atomicAdd(&deg[dst], 1);
}

__global__ void scan_kernel(const int* __restrict__ deg, int* __restrict__ rowptr,
                            int* __restrict__ cursor, int n) {
    __shared__ int wsum[16];
    int t = threadIdx.x;
    int lane = t & 63, wid = t >> 6;
    int carry = 0;
    for (int base = 0; base < n; base += 1024) {
        int i = base + t;
        int v = (i < n) ? ((deg[i] + 7) & ~7) : 0;   // padded degree
        int val = v;
        #pragma unroll
        for (int off = 1; off < 64; off <<= 1) {
            int nv = __shfl_up(val, off);
            if (lane >= off) val += nv;
        }
        if (lane == 63) wsum[wid] = val;
        __syncthreads();
        int wpre = 0, tot = 0;
        #pragma unroll
        for (int w = 0; w < 16; ++w) {
            int s = wsum[w];
            if (w < wid) wpre += s;
            tot += s;
        }
        int excl = carry + wpre + val - v;
        if (i < n) { rowptr[i] = excl; cursor[i] = excl; }
        carry += tot;
        __syncthreads();
    }
    if (t == 0) rowptr[n] = carry;
}

__global__ void scatter_kernel(const int* __restrict__ ei, int E, int n,
                               int* __restrict__ cursor, int* __restrict__ ssrc) {
    int e = blockIdx.x * blockDim.x + threadIdx.x;
    int Etot = E + n;
    if (e >= Etot) return;
    int src, dst;
    if (e < E) { src = ei[e]; dst = ei[E + e]; }
    else       { src = e - E; dst = e - E; }
    int pos = atomicAdd(&cursor[dst], 1);
    ssrc[pos] = src;
}

__global__ void pad_fill_kernel(const int* __restrict__ rowptr, const int* __restrict__ cursor,
                                int* __restrict__ ssrc, int n) {
    int i = blockIdx.x * blockDim.x + threadIdx.x;
    if (i >= n) return;
    int p = cursor[i], e = rowptr[i + 1];
    for (; p < e; ++p) ssrc[p] = n;   // sentinel
}

// ---------------- bf16 MFMA NT GEMM + fused attention logits, fp8 feature output ----------------
// B has NFRAG*16 rows: first (NFRAG-1)*16 = W rows -> C (fp8 e4m3); last 16 = wa rows -> als/ald (f32).

template<int NFRAG, int K>
__global__ __launch_bounds__(512) void gemm_lds_al(const ushort_t* __restrict__ A,
                                                   const ushort_t* __restrict__ B,
                                                   uchar_t* __restrict__ C,
                                                   float* __restrict__ als,
                                                   float* __restrict__ ald, int M) {
    constexpr int N = NFRAG * 16;
    constexpr int NOUT = (NFRAG - 1) * 16;
    constexpr int RS = 40;                 // LDS row stride in elems
    constexpr int NK = K / 32;
    __shared__ ushort_t Bs[2][N * RS];
    const int t = threadIdx.x;
    const int w = t >> 6, l = t & 63;
    const int r0 = blockIdx.x * 128 + w * 16;
    int arow = r0 + (l & 15);
    if (arow >= M) arow = M - 1;
    const int koff = (l >> 4) * 8;
    const ushort_t* ap = A + (size_t)arow * K + koff;

    f32x4 acc[NFRAG];
    #pragma unroll
    for (int i = 0; i < NFRAG; ++i) acc[i] = (f32x4){0.f, 0.f, 0.f, 0.f};

    auto stage = [&](int buf, int k0) {
        #pragma unroll
        for (int c = t; c < N * 4; c += 512) {
            int row = c >> 2, part = (c & 3) << 3;           // part in elems
            *(short8*)&Bs[buf][row * RS + part] =
                *(const short8*)(B + (size_t)row * K + k0 + part);
        }
    };

    stage(0, 0);
    __syncthreads();
    #pragma unroll
    for (int kk = 0; kk < NK; ++kk) {
        int buf = kk & 1;
        if (kk + 1 < NK) stage(buf ^ 1, (kk + 1) * 32);
        short8 a = *(const short8*)(ap + kk * 32);
        #pragma unroll
        for (int nf = 0; nf < NFRAG; ++nf) {
            short8 b = *(const short8*)&Bs[buf][(nf * 16 + (l & 15)) * RS + koff];
            acc[nf] = __builtin_amdgcn_mfma_f32_16x16x32_bf16(a, b, acc[nf], 0, 0, 0);
        }
        __syncthreads();
    }

    const int crow0 = r0 + (l >> 4) * 4;
    #pragma unroll
    for (int nf = 0; nf < NFRAG - 1; ++nf) {
        #pragma unroll
        for (int j = 0; j < 4; ++j) {
            int row = crow0 + j;
            if (row < M) C[(size_t)row * NOUT + nf * 16 + (l & 15)] = f2e4m3(acc[nf][j]);
        }
    }
    {   // attention-logit fragment
        int col = l & 15;
        float* dstp = (col < 8) ? als : ald;
        int h = col & 7;
        #pragma unroll
        for (int j = 0; j < 4; ++j) {
            int row = crow0 + j;
            if (row < M) dstp[(size_t)row * 8 + h] = acc[NFRAG - 1][j];
        }
    }
}

// ---------------- layer-1 aggregation: 8-edge unrolled online softmax, fp8 gather ----------------

__device__ __forceinline__ float lrelu(float e) { return (e > 0.f) ? e : 0.2f * e; }

__global__ void agg1_kernel(const uchar_t* __restrict__ h1, const float* __restrict__ als,
                            const float* __restrict__ aldv, const float* __restrict__ b1,
                            const int* __restrict__ rowptr, const int* __restrict__ ssrc,
                            ushort_t* __restrict__ hout, int n) {
    int node = blockIdx.x * 4 + (threadIdx.x >> 6);
    if (node >= n) return;
    int l = threadIdx.x & 63;
    int h = l >> 3;
    float ald = aldv[node * 8 + h];
    int beg = rowptr[node], end = rowptr[node + 1];
    float m = -1e30f, den = 0.f, a0 = 0.f, a1 = 0.f, a2 = 0.f, a3 = 0.f;
    for (int p = beg; p < end; p += 8) {
        int4 sA = *(const int4*)(ssrc + p);
        int4 sB = *(const int4*)(ssrc + p + 4);
        float e0 = lrelu(als[sA.x * 8 + h] + ald);
        float e1 = lrelu(als[sA.y * 8 + h] + ald);
        float e2 = lrelu(als[sA.z * 8 + h] + ald);
        float e3 = lrelu(als[sA.w * 8 + h] + ald);
        float e4 = lrelu(als[sB.x * 8 + h] + ald);
        float e5 = lrelu(als[sB.y * 8 + h] + ald);
        float e6 = lrelu(als[sB.z * 8 + h] + ald);
        float e7 = lrelu(als[sB.w * 8 + h] + ald);
        int g0 = *(const int*)(h1 + (size_t)sA.x * 256 + l * 4);
        int g1 = *(const int*)(h1 + (size_t)sA.y * 256 + l * 4);
        int g2 = *(const int*)(h1 + (size_t)sA.z * 256 + l * 4);
        int g3 = *(const int*)(h1 + (size_t)sA.w * 256 + l * 4);
        int g4 = *(const int*)(h1 + (size_t)sB.x * 256 + l * 4);
        int g5 = *(const int*)(h1 + (size_t)sB.y * 256 + l * 4);
        int g6 = *(const int*)(h1 + (size_t)sB.z * 256 + l * 4);
        int g7 = *(const int*)(h1 + (size_t)sB.w * 256 + l * 4);
        float em = fmaxf(fmaxf(fmaxf(e0, e1), fmaxf(e2, e3)),
                         fmaxf(fmaxf(e4, e5), fmaxf(e6, e7)));
        if (em > m + 8.f) {
            float f = __expf(m - em);
            den *= f; a0 *= f; a1 *= f; a2 *= f; a3 *= f;
            m = em;
        }
        float w0 = __expf(e0 - m), w1 = __expf(e1 - m);
        float w2 = __expf(e2 - m), w3 = __expf(e3 - m);
        float w4 = __expf(e4 - m), w5 = __expf(e5 - m);
        float w6 = __expf(e6 - m), w7 = __expf(e7 - m);
        den += ((w0 + w1) + (w2 + w3)) + ((w4 + w5) + (w6 + w7));
        #define DQ(g, wv) { \
            f32x2 lo = __builtin_amdgcn_cvt_pk_f32_fp8(g, false); \
            f32x2 hi = __builtin_amdgcn_cvt_pk_f32_fp8(g, true);  \
            a0 += wv * lo.x; a1 += wv * lo.y; a2 += wv * hi.x; a3 += wv * hi.y; }
        DQ(g0, w0) DQ(g1, w1) DQ(g2, w2) DQ(g3, w3)
        DQ(g4, w4) DQ(g5, w5) DQ(g6, w6) DQ(g7, w7)
        #undef DQ
    }
    float inv = 1.f / den;
    float4 bv = *(const float4*)(b1 + l * 4);
    float v0 = a0 * inv + bv.x, v1 = a1 * inv + bv.y;
    float v2 = a2 * inv + bv.z, v3 = a3 * inv + bv.w;
    u16x4 o;
    o.x = f2b((v0 > 0.f) ? v0 : __expf(v0) - 1.f);
    o.y = f2b((v1 > 0.f) ? v1 : __expf(v1) - 1.f);
    o.z = f2b((v2 > 0.f) ? v2 : __expf(v2) - 1.f);
    o.w = f2b((v3 > 0.f) ? v3 : __expf(v3) - 1.f);
    *(u16x4*)(hout + (size_t)node * 256 + l * 4) = o;
}

// ---------------- layer-2 aggregation: 8-edge unrolled fp8 gather + head-mean + log_softmax ----------------

__global__ void agg2_kernel(const uchar_t* __restrict__ h2, const float* __restrict__ als,
                            const float* __restrict__ aldv, const float* __restrict__ b2,
                            const int* __restrict__ rowptr, const int* __restrict__ ssrc,
                            float* __restrict__ out, int n) {
    int node = blockIdx.x * 4 + (threadIdx.x >> 6);
    if (node >= n) return;
    int l = threadIdx.x & 63;
    int li = (l < 40) ? l : 0;
    int hd = li / 5;
    int cg = li - hd * 5;
    float ald = aldv[node * 8 + hd];
    int beg = rowptr[node], end = rowptr[node + 1];
    const uchar_t* base = h2 + hd * 40 + cg * 8;
    float m = -1e30f, den = 0.f;
    float a0 = 0.f, a1 = 0.f, a2 = 0.f, a3 = 0.f, a4 = 0.f, a5 = 0.f, a6 = 0.f, a7 = 0.f;
    for (int p = beg; p < end; p += 8) {
        int4 sA = *(const int4*)(ssrc + p);
        int4 sB = *(const int4*)(ssrc + p + 4);
        float e0 = lrelu(als[sA.x * 8 + hd] + ald);
        float e1 = lrelu(als[sA.y * 8 + hd] + ald);
        float e2 = lrelu(als[sA.z * 8 + hd] + ald);
        float e3 = lrelu(als[sA.w * 8 + hd] + ald);
        float e4 = lrelu(als[sB.x * 8 + hd] + ald);
        float e5 = lrelu(als[sB.y * 8 + hd] + ald);
        float e6 = lrelu(als[sB.z * 8 + hd] + ald);
        float e7 = lrelu(als[sB.w * 8 + hd] + ald);
        uint2 g0 = *(const uint2*)(base + (size_t)sA.x * 320);
        uint2 g1 = *(const uint2*)(base + (size_t)sA.y * 320);
        uint2 g2 = *(const uint2*)(base + (size_t)sA.z * 320);
        uint2 g3 = *(const uint2*)(base + (size_t)sA.w * 320);
        uint2 g4 = *(const uint2*)(base + (size_t)sB.x * 320);
        uint2 g5 = *(const uint2*)(base + (size_t)sB.y * 320);
        uint2 g6 = *(const uint2*)(base + (size_t)sB.z * 320);
        uint2 g7 = *(const uint2*)(base + (size_t)sB.w * 320);
        float em = fmaxf(fmaxf(fmaxf(e0, e1), fmaxf(e2, e3)),
                         fmaxf(fmaxf(e4, e5), fmaxf(e6, e7)));
        if (em > m + 8.f) {
            float f = __expf(m - em);
            den *= f;
            a0 *= f; a1 *= f; a2 *= f; a3 *= f; a4 *= f; a5 *= f; a6 *= f; a7 *= f;
            m = em;
        }
        float w0 = __expf(e0 - m), w1 = __expf(e1 - m);
        float w2 = __expf(e2 - m), w3 = __expf(e3 - m);
        float w4 = __expf(e4 - m), w5 = __expf(e5 - m);
        float w6 = __expf(e6 - m), w7 = __expf(e7 - m);
        den += ((w0 + w1) + (w2 + w3)) + ((w4 + w5) + (w6 + w7));
        #define DQ(g, wv) { \
            f32x2 q0 = __builtin_amdgcn_cvt_pk_f32_fp8((int)g.x, false); \
            f32x2 q1 = __builtin_amdgcn_cvt_pk_f32_fp8((int)g.x, true);  \
            f32x2 q2 = __builtin_amdgcn_cvt_pk_f32_fp8((int)g.y, false); \
            f32x2 q3 = __builtin_amdgcn_cvt_pk_f32_fp8((int)g.y, true);  \
            a0 += wv * q0.x; a1 += wv * q0.y; a2 += wv * q1.x; a3 += wv * q1.y; \
            a4 += wv * q2.x; a5 += wv * q2.y; a6 += wv * q3.x; a7 += wv * q3.y; }
        DQ(g0, w0) DQ(g1, w1) DQ(g2, w2) DQ(g3, w3)
        DQ(g4, w4) DQ(g5, w5) DQ(g6, w6) DQ(g7, w7)
        #undef DQ
    }
    float inv = 1.f / den;
    float v[8] = {a0 * inv, a1 * inv, a2 * inv, a3 * inv,
                  a4 * inv, a5 * inv, a6 * inv, a7 * inv};
    #pragma unroll
    for (int j = 0; j < 8; ++j) {
        float s = v[j];
        s += __shfl_down(s, 20);
        s += __shfl_down(s, 10);
        s += __shfl_down(s, 5);
        v[j] = s;
    }
    if (l < 5) {
        float wv[8];
        #pragma unroll
        for (int j = 0; j < 8; ++j) wv[j] = 0.125f * v[j] + b2[l * 8 + j];
        float m8 = wv[0];
        #pragma unroll
        for (int j = 1; j < 8; ++j) m8 = fmaxf(m8, wv[j]);
        float mx = m8;
        #pragma unroll
        for (int k = 0; k < 5; ++k) mx = fmaxf(mx, __shfl(m8, k));
        float se8 = 0.f;
        #pragma unroll
        for (int j = 0; j < 8; ++j) se8 += __expf(wv[j] - mx);
        float se = 0.f;
        #pragma unroll
        for (int k = 0; k < 5; ++k) se += __shfl(se8, k);
        float lse = mx + __logf(se);
        float* op = out + (size_t)node * 40 + l * 8;
        float4 o0 = {wv[0] - lse, wv[1] - lse, wv[2] - lse, wv[3] - lse};
        float4 o1 = {wv[4] - lse, wv[5] - lse, wv[6] - lse, wv[7] - lse};
        *(float4*)op = o0;
        *(float4*)(op + 4) = o1;
    }
}

// ---------------- launch ----------------

extern "C" void kernel_launch(void* const* d_in, const int* in_sizes, int n_in,
                              void* d_out, int out_size, void* d_ws, size_t ws_size,
                              hipStream_t stream) {
    const float* x      = (const float*)d_in[0];
    const int*   ei     = (const int*)d_in[1];
    const float* W1     = (const float*)d_in[2];
    const float* a_src1 = (const float*)d_in[3];
    const float* a_dst1 = (const float*)d_in[4];
    const float* b1     = (const float*)d_in[5];
    const float* W2     = (const float*)d_in[6];
    const float* a_src2 = (const float*)d_in[7];
    const float* a_dst2 = (const float*)d_in[8];
    const float* b2     = (const float*)d_in[9];
    float* out = (float*)d_out;

    const int n    = in_sizes[0] / 128;   // 50000
    const int E    = in_sizes[1] / 2;     // 800000
    const int Etot = E + n;
    const int EpM  = Etot + 7 * n + 16;   // upper bound on padded edge count

    char* w = (char*)d_ws;
    auto take = [&](size_t bytes) {
        char* p = w;
        w += (bytes + 255) & ~(size_t)255;
        return p;
    };
    int*      deg    = (int*)take((size_t)n * 4);
    int*      rowptr = (int*)take((size_t)(n + 1) * 4);
    int*      cursor = (int*)take((size_t)n * 4);
    int*      ssrc   = (int*)take((size_t)EpM * 4);
    ushort_t* xb     = (ushort_t*)take((size_t)n * 128 * 2);
    ushort_t* w1b    = (ushort_t*)take((size_t)272 * 128 * 2);   // 256 W1 rows + 16 wa rows
    ushort_t* w2b    = (ushort_t*)take((size_t)336 * 256 * 2);   // 320 W2 rows + 16 wa rows
    uchar_t*  h1f8   = (uchar_t*)take((size_t)(n + 1) * 256);
    ushort_t* helu   = (ushort_t*)take((size_t)n * 256 * 2);
    uchar_t*  h2f8   = (uchar_t*)take((size_t)(n + 1) * 320);
    float*    als1   = (float*)take((size_t)(n + 1) * 8 * 4);
    float*    ald1   = (float*)take((size_t)n * 8 * 4);
    float*    als2   = (float*)take((size_t)(n + 1) * 8 * 4);
    float*    ald2   = (float*)take((size_t)n * 8 * 4);

    hipMemsetAsync(deg, 0, (size_t)n * 4, stream);
    pad_row_kernel<<<1, 512, 0, stream>>>(als1, als2, h1f8, h2f8, n);

    // dtype converts + folded attention rows
    conv_kernel<<<2048, 256, 0, stream>>>(x, xb, n * 128 / 4);
    conv_kernel<<<32, 256, 0, stream>>>(W1, w1b, 256 * 128 / 4);
    conv_kernel<<<80, 256, 0, stream>>>(W2, w2b, 320 * 256 / 4);
    build_wa<128, 32><<<8, 256, 0, stream>>>(W1, a_src1, a_dst1, w1b, 256);
    build_wa<256, 40><<<16, 256, 0, stream>>>(W2, a_src2, a_dst2, w2b, 320);

    // CSR (8-padded rows)
    int eb = (Etot + 255) / 256;
    count_kernel<<<eb, 256, 0, stream>>>(ei, E, n, deg);
    scan_kernel<<<1, 1024, 0, stream>>>(deg, rowptr, cursor, n);
    scatter_kernel<<<eb, 256, 0, stream>>>(ei, E, n, cursor, ssrc);
    pad_fill_kernel<<<(n + 255) / 256, 256, 0, stream>>>(rowptr, cursor, ssrc, n);

    int gb = (n + 127) / 128;
    int nb4 = (n + 3) / 4;

    // layer 1 (gemm computes fp8 h1 AND f32 als1/ald1)
    gemm_lds_al<17, 128><<<gb, 512, 0, stream>>>(xb, w1b, h1f8, als1, ald1, n);
    agg1_kernel<<<nb4, 256, 0, stream>>>(h1f8, als1, ald1, b1, rowptr, ssrc, helu, n);

    // layer 2
    gemm_lds_al<21, 256><<<gb, 512, 0, stream>>>(helu, w2b, h2f8, als2, ald2, n);
    agg2_kernel<<<nb4, 256, 0, stream>>>(h2f8, als2, ald2, b2, rowptr, ssrc, out, n);
}

// Round 13
// 306.294 us; speedup vs baseline: 1.3353x; 1.0055x over previous
//
#include <hip/hip_runtime.h>
#include <hip/hip_bf16.h>
#include <math.h>

typedef unsigned short ushort_t;
typedef unsigned char uchar_t;
typedef __attribute__((ext_vector_type(8))) short short8;
typedef __attribute__((ext_vector_type(4))) float f32x4;
typedef __attribute__((ext_vector_type(2))) float f32x2;
typedef __attribute__((ext_vector_type(4))) unsigned short u16x4;

#define LOG2E 1.44269504088896f

static __device__ __forceinline__ float b2f(ushort_t u) {
    union { unsigned int i; float f; } v; v.i = ((unsigned int)u) << 16; return v.f;
}
static __device__ __forceinline__ ushort_t f2b(float f) {
    unsigned int x = __float_as_uint(f);
    unsigned int r = (x + 0x7fffu + ((x >> 16) & 1u)) >> 16;
    return (ushort_t)r;
}
static __device__ __forceinline__ uchar_t f2e4m3(float f) {
    int r = __builtin_amdgcn_cvt_pk_fp8_f32(f, f, 0, false);
    return (uchar_t)(r & 0xff);
}
static __device__ __forceinline__ float exp2fast(float x) {
    return __builtin_amdgcn_exp2f(x);     // v_exp_f32 (2^x); avoids glibc __exp2f macro clash
}

// ---------------- fp32 -> bf16 convert ----------------

__global__ void conv_kernel(const float* __restrict__ src, ushort_t* __restrict__ dst, int n4) {
    for (int i = blockIdx.x * blockDim.x + threadIdx.x; i < n4; i += gridDim.x * blockDim.x) {
        float4 v = *(const float4*)(src + i * 4);
        u16x4 o = { f2b(v.x), f2b(v.y), f2b(v.z), f2b(v.w) };
        *(u16x4*)(dst + i * 4) = o;
    }
}

// folded attention rows, pre-scaled by log2(e) so agg kernels can use exp2 directly
template<int K, int Cd>
__global__ void build_wa(const float* __restrict__ W, const float* __restrict__ as,
                         const float* __restrict__ ad, ushort_t* __restrict__ Bext, int rowoff) {
    int tid = blockIdx.x * blockDim.x + threadIdx.x;
    if (tid >= 16 * K) return;
    int col = tid / K, k = tid - col * K;
    const float* a = (col < 8) ? as : ad;
    int h = col & 7;
    float s = 0.f;
    #pragma unroll 4
    for (int c = 0; c < Cd; ++c)
        s += W[(size_t)(h * Cd + c) * K + k] * a[h * Cd + c];
    Bext[(size_t)(rowoff + col) * K + k] = f2b(s * LOG2E);
}

// pad rows: als1/als2 row n = -1e30 (sentinel -> zero weight), h1/h2 fp8 row n = 0
__global__ void pad_row_kernel(float* als1, float* als2, uchar_t* h1f8, uchar_t* h2f8, int n) {
    int t = threadIdx.x;
    if (t < 8) { als1[(size_t)n * 8 + t] = -1e30f; als2[(size_t)n * 8 + t] = -1e30f; }
    if (t < 256) h1f8[(size_t)n * 256 + t] = 0;
    if (t < 320) h2f8[(size_t)n * 320 + t] = 0;
}

// ---------------- CSR build (rows padded to multiples of 8) ----------------

__global__ void count_kernel(const int* __restrict__ ei, int E, int n, int* __restrict__ deg) {
    int e = blockIdx.x * blockDim.x + threadIdx.x;
    int Etot = E + n;
    if (e >= Etot) return;
    int dst = (e < E) ? ei[E + e] : (e - E);
    atomicAdd(&deg[dst], 1);
}

__global__ void scan_kernel(const int* __restrict__ deg, int* __restrict__ rowptr,
                            int* __restrict__ cursor, int n) {
    __shared__ int wsum[16];
    int t = threadIdx.x;
    int lane = t & 63, wid = t >> 6;
    int carry = 0;
    for (int base = 0; base < n; base += 1024) {
        int i = base + t;
        int v = (i < n) ? ((deg[i] + 7) & ~7) : 0;   // padded degree
        int val = v;
        #pragma unroll
        for (int off = 1; off < 64; off <<= 1) {
            int nv = __shfl_up(val, off);
            if (lane >= off) val += nv;
        }
        if (lane == 63) wsum[wid] = val;
        __syncthreads();
        int wpre = 0, tot = 0;
        #pragma unroll
        for (int w = 0; w < 16; ++w) {
            int s = wsum[w];
            if (w < wid) wpre += s;
            tot += s;
        }
        int excl = carry + wpre + val - v;
        if (i < n) { rowptr[i] = excl; cursor[i] = excl; }
        carry += tot;
        __syncthreads();
    }
    if (t == 0) rowptr[n] = carry;
}

__global__ void scatter_kernel(const int* __restrict__ ei, int E, int n,
                               int* __restrict__ cursor, int* __restrict__ ssrc) {
    int e = blockIdx.x * blockDim.x + threadIdx.x;
    int Etot = E + n;
    if (e >= Etot) return;
    int src, dst;
    if (e < E) { src = ei[e]; dst = ei[E + e]; }
    else       { src = e - E; dst = e - E; }
    int pos = atomicAdd(&cursor[dst], 1);
    ssrc[pos] = src;
}

__global__ void pad_fill_kernel(const int* __restrict__ rowptr, const int* __restrict__ cursor,
                                int* __restrict__ ssrc, int n) {
    int i = blockIdx.x * blockDim.x + threadIdx.x;
    if (i >= n) return;
    int p = cursor[i], e = rowptr[i + 1];
    for (; p < e; ++p) ssrc[p] = n;   // sentinel
}

// ---------------- bf16 MFMA NT GEMM + fused attention logits, fp8 feature output ----------------
// BM = 256 rows (8 waves x 2 row-groups of 16). B k-slice double-buffered in LDS.

template<int NFRAG, int K>
__global__ __launch_bounds__(512) void gemm_lds_al(const ushort_t* __restrict__ A,
                                                   const ushort_t* __restrict__ B,
                                                   uchar_t* __restrict__ C,
                                                   float* __restrict__ als,
                                                   float* __restrict__ ald, int M) {
    constexpr int N = NFRAG * 16;
    constexpr int NOUT = (NFRAG - 1) * 16;
    constexpr int RS = 40;                 // LDS row stride in elems
    constexpr int NK = K / 32;
    __shared__ ushort_t Bs[2][N * RS];
    const int t = threadIdx.x;
    const int w = t >> 6, l = t & 63;
    const int r0 = blockIdx.x * 256 + w * 32;
    int arow0 = r0 + (l & 15);
    int arow1 = r0 + 16 + (l & 15);
    if (arow0 >= M) arow0 = M - 1;
    if (arow1 >= M) arow1 = M - 1;
    const int koff = (l >> 4) * 8;
    const ushort_t* ap0 = A + (size_t)arow0 * K + koff;
    const ushort_t* ap1 = A + (size_t)arow1 * K + koff;

    f32x4 acc0[NFRAG], acc1[NFRAG];
    #pragma unroll
    for (int i = 0; i < NFRAG; ++i) {
        acc0[i] = (f32x4){0.f, 0.f, 0.f, 0.f};
        acc1[i] = (f32x4){0.f, 0.f, 0.f, 0.f};
    }

    auto stage = [&](int buf, int k0) {
        #pragma unroll
        for (int c = t; c < N * 4; c += 512) {
            int row = c >> 2, part = (c & 3) << 3;           // part in elems
            *(short8*)&Bs[buf][row * RS + part] =
                *(const short8*)(B + (size_t)row * K + k0 + part);
        }
    };

    stage(0, 0);
    __syncthreads();
    #pragma unroll
    for (int kk = 0; kk < NK; ++kk) {
        int buf = kk & 1;
        if (kk + 1 < NK) stage(buf ^ 1, (kk + 1) * 32);
        short8 a0 = *(const short8*)(ap0 + kk * 32);
        short8 a1 = *(const short8*)(ap1 + kk * 32);
        #pragma unroll
        for (int nf = 0; nf < NFRAG; ++nf) {
            short8 b = *(const short8*)&Bs[buf][(nf * 16 + (l & 15)) * RS + koff];
            acc0[nf] = __builtin_amdgcn_mfma_f32_16x16x32_bf16(a0, b, acc0[nf], 0, 0, 0);
            acc1[nf] = __builtin_amdgcn_mfma_f32_16x16x32_bf16(a1, b, acc1[nf], 0, 0, 0);
        }
        __syncthreads();
    }

    const int crow0 = r0 + (l >> 4) * 4;
    #pragma unroll
    for (int nf = 0; nf < NFRAG - 1; ++nf) {
        #pragma unroll
        for (int j = 0; j < 4; ++j) {
            int row0 = crow0 + j, row1 = crow0 + 16 + j;
            if (row0 < M) C[(size_t)row0 * NOUT + nf * 16 + (l & 15)] = f2e4m3(acc0[nf][j]);
            if (row1 < M) C[(size_t)row1 * NOUT + nf * 16 + (l & 15)] = f2e4m3(acc1[nf][j]);
        }
    }
    {   // attention-logit fragment (pre-scaled by log2e)
        int col = l & 15;
        float* dstp = (col < 8) ? als : ald;
        int h = col & 7;
        #pragma unroll
        for (int j = 0; j < 4; ++j) {
            int row0 = crow0 + j, row1 = crow0 + 16 + j;
            if (row0 < M) dstp[(size_t)row0 * 8 + h] = acc0[NFRAG - 1][j];
            if (row1 < M) dstp[(size_t)row1 * 8 + h] = acc1[NFRAG - 1][j];
        }
    }
}

// ---------------- layer-1 aggregation: 8-edge unrolled, no-max exp2 softmax, fp8 gather ----------------

__device__ __forceinline__ float lrelu(float e) { return (e > 0.f) ? e : 0.2f * e; }

__global__ void agg1_kernel(const uchar_t* __restrict__ h1, const float* __restrict__ als,
                            const float* __restrict__ aldv, const float* __restrict__ b1,
                            const int* __restrict__ rowptr, const int* __restrict__ ssrc,
                            ushort_t* __restrict__ hout, int n) {
    int node = blockIdx.x * 4 + (threadIdx.x >> 6);
    if (node >= n) return;
    int l = threadIdx.x & 63;
    int h = l >> 3;
    float ald = aldv[node * 8 + h];
    int beg = rowptr[node], end = rowptr[node + 1];
    float den = 0.f, a0 = 0.f, a1 = 0.f, a2 = 0.f, a3 = 0.f;
    for (int p = beg; p < end; p += 8) {
        int4 sA = *(const int4*)(ssrc + p);
        int4 sB = *(const int4*)(ssrc + p + 4);
        float w0 = exp2fast(lrelu(als[sA.x * 8 + h] + ald));
        float w1 = exp2fast(lrelu(als[sA.y * 8 + h] + ald));
        float w2 = exp2fast(lrelu(als[sA.z * 8 + h] + ald));
        float w3 = exp2fast(lrelu(als[sA.w * 8 + h] + ald));
        float w4 = exp2fast(lrelu(als[sB.x * 8 + h] + ald));
        float w5 = exp2fast(lrelu(als[sB.y * 8 + h] + ald));
        float w6 = exp2fast(lrelu(als[sB.z * 8 + h] + ald));
        float w7 = exp2fast(lrelu(als[sB.w * 8 + h] + ald));
        int g0 = *(const int*)(h1 + (size_t)sA.x * 256 + l * 4);
        int g1 = *(const int*)(h1 + (size_t)sA.y * 256 + l * 4);
        int g2 = *(const int*)(h1 + (size_t)sA.z * 256 + l * 4);
        int g3 = *(const int*)(h1 + (size_t)sA.w * 256 + l * 4);
        int g4 = *(const int*)(h1 + (size_t)sB.x * 256 + l * 4);
        int g5 = *(const int*)(h1 + (size_t)sB.y * 256 + l * 4);
        int g6 = *(const int*)(h1 + (size_t)sB.z * 256 + l * 4);
        int g7 = *(const int*)(h1 + (size_t)sB.w * 256 + l * 4);
        den += ((w0 + w1) + (w2 + w3)) + ((w4 + w5) + (w6 + w7));
        #define DQ(g, wv) { \
            f32x2 lo = __builtin_amdgcn_cvt_pk_f32_fp8(g, false); \
            f32x2 hi = __builtin_amdgcn_cvt_pk_f32_fp8(g, true);  \
            a0 += wv * lo.x; a1 += wv * lo.y; a2 += wv * hi.x; a3 += wv * hi.y; }
        DQ(g0, w0) DQ(g1, w1) DQ(g2, w2) DQ(g3, w3)
        DQ(g4, w4) DQ(g5, w5) DQ(g6, w6) DQ(g7, w7)
        #undef DQ
    }
    float inv = 1.f / den;
    float4 bv = *(const float4*)(b1 + l * 4);
    float v0 = a0 * inv + bv.x, v1 = a1 * inv + bv.y;
    float v2 = a2 * inv + bv.z, v3 = a3 * inv + bv.w;
    u16x4 o;
    o.x = f2b((v0 > 0.f) ? v0 : __expf(v0) - 1.f);
    o.y = f2b((v1 > 0.f) ? v1 : __expf(v1) - 1.f);
    o.z = f2b((v2 > 0.f) ? v2 : __expf(v2) - 1.f);
    o.w = f2b((v3 > 0.f) ? v3 : __expf(v3) - 1.f);
    *(u16x4*)(hout + (size_t)node * 256 + l * 4) = o;
}

// ---------------- layer-2 aggregation: 8-edge unrolled fp8 gather + head-mean + log_softmax ----------------

__global__ void agg2_kernel(const uchar_t* __restrict__ h2, const float* __restrict__ als,
                            const float* __restrict__ aldv, const float* __restrict__ b2,
                            const int* __restrict__ rowptr, const int* __restrict__ ssrc,
                            float* __restrict__ out, int n) {
    int node = blockIdx.x * 4 + (threadIdx.x >> 6);
    if (node >= n) return;
    int l = threadIdx.x & 63;
    int li = (l < 40) ? l : 0;
    int hd = li / 5;
    int cg = li - hd * 5;
    float ald = aldv[node * 8 + hd];
    int beg = rowptr[node], end = rowptr[node + 1];
    const uchar_t* base = h2 + hd * 40 + cg * 8;
    float den = 0.f;
    float a0 = 0.f, a1 = 0.f, a2 = 0.f, a3 = 0.f, a4 = 0.f, a5 = 0.f, a6 = 0.f, a7 = 0.f;
    for (int p = beg; p < end; p += 8) {
        int4 sA = *(const int4*)(ssrc + p);
        int4 sB = *(const int4*)(ssrc + p + 4);
        float w0 = exp2fast(lrelu(als[sA.x * 8 + hd] + ald));
        float w1 = exp2fast(lrelu(als[sA.y * 8 + hd] + ald));
        float w2 = exp2fast(lrelu(als[sA.z * 8 + hd] + ald));
        float w3 = exp2fast(lrelu(als[sA.w * 8 + hd] + ald));
        float w4 = exp2fast(lrelu(als[sB.x * 8 + hd] + ald));
        float w5 = exp2fast(lrelu(als[sB.y * 8 + hd] + ald));
        float w6 = exp2fast(lrelu(als[sB.z * 8 + hd] + ald));
        float w7 = exp2fast(lrelu(als[sB.w * 8 + hd] + ald));
        uint2 g0 = *(const uint2*)(base + (size_t)sA.x * 320);
        uint2 g1 = *(const uint2*)(base + (size_t)sA.y * 320);
        uint2 g2 = *(const uint2*)(base + (size_t)sA.z * 320);
        uint2 g3 = *(const uint2*)(base + (size_t)sA.w * 320);
        uint2 g4 = *(const uint2*)(base + (size_t)sB.x * 320);
        uint2 g5 = *(const uint2*)(base + (size_t)sB.y * 320);
        uint2 g6 = *(const uint2*)(base + (size_t)sB.z * 320);
        uint2 g7 = *(const uint2*)(base + (size_t)sB.w * 320);
        den += ((w0 + w1) + (w2 + w3)) + ((w4 + w5) + (w6 + w7));
        #define DQ(g, wv) { \
            f32x2 q0 = __builtin_amdgcn_cvt_pk_f32_fp8((int)g.x, false); \
            f32x2 q1 = __builtin_amdgcn_cvt_pk_f32_fp8((int)g.x, true);  \
            f32x2 q2 = __builtin_amdgcn_cvt_pk_f32_fp8((int)g.y, false); \
            f32x2 q3 = __builtin_amdgcn_cvt_pk_f32_fp8((int)g.y, true);  \
            a0 += wv * q0.x; a1 += wv * q0.y; a2 += wv * q1.x; a3 += wv * q1.y; \
            a4 += wv * q2.x; a5 += wv * q2.y; a6 += wv * q3.x; a7 += wv * q3.y; }
        DQ(g0, w0) DQ(g1, w1) DQ(g2, w2) DQ(g3, w3)
        DQ(g4, w4) DQ(g5, w5) DQ(g6, w6) DQ(g7, w7)
        #undef DQ
    }
    float inv = 1.f / den;
    float v[8] = {a0 * inv, a1 * inv, a2 * inv, a3 * inv,
                  a4 * inv, a5 * inv, a6 * inv, a7 * inv};
    #pragma unroll
    for (int j = 0; j < 8; ++j) {
        float s = v[j];
        s += __shfl_down(s, 20);
        s += __shfl_down(s, 10);
        s += __shfl_down(s, 5);
        v[j] = s;
    }
    if (l < 5) {
        float wv[8];
        #pragma unroll
        for (int j = 0; j < 8; ++j) wv[j] = 0.125f * v[j] + b2[l * 8 + j];
        float m8 = wv[0];
        #pragma unroll
        for (int j = 1; j < 8; ++j) m8 = fmaxf(m8, wv[j]);
        float mx = m8;
        #pragma unroll
        for (int k = 0; k < 5; ++k) mx = fmaxf(mx, __shfl(m8, k));
        float se8 = 0.f;
        #pragma unroll
        for (int j = 0; j < 8; ++j) se8 += __expf(wv[j] - mx);
        float se = 0.f;
        #pragma unroll
        for (int k = 0; k < 5; ++k) se += __shfl(se8, k);
        float lse = mx + __logf(se);
        float* op = out + (size_t)node * 40 + l * 8;
        float4 o0 = {wv[0] - lse, wv[1] - lse, wv[2] - lse, wv[3] - lse};
        float4 o1 = {wv[4] - lse, wv[5] - lse, wv[6] - lse, wv[7] - lse};
        *(float4*)op = o0;
        *(float4*)(op + 4) = o1;
    }
}

// ---------------- launch ----------------

extern "C" void kernel_launch(void* const* d_in, const int* in_sizes, int n_in,
                              void* d_out, int out_size, void* d_ws, size_t ws_size,
                              hipStream_t stream) {
    const float* x      = (const float*)d_in[0];
    const int*   ei     = (const int*)d_in[1];
    const float* W1     = (const float*)d_in[2];
    const float* a_src1 = (const float*)d_in[3];
    const float* a_dst1 = (const float*)d_in[4];
    const float* b1     = (const float*)d_in[5];
    const float* W2     = (const float*)d_in[6];
    const float* a_src2 = (const float*)d_in[7];
    const float* a_dst2 = (const float*)d_in[8];
    const float* b2     = (const float*)d_in[9];
    float* out = (float*)d_out;

    const int n    = in_sizes[0] / 128;   // 50000
    const int E    = in_sizes[1] / 2;     // 800000
    const int Etot = E + n;
    const int EpM  = Etot + 7 * n + 16;   // upper bound on padded edge count

    char* w = (char*)d_ws;
    auto take = [&](size_t bytes) {
        char* p = w;
        w += (bytes + 255) & ~(size_t)255;
        return p;
    };
    int*      deg    = (int*)take((size_t)n * 4);
    int*      rowptr = (int*)take((size_t)(n + 1) * 4);
    int*      cursor = (int*)take((size_t)n * 4);
    int*      ssrc   = (int*)take((size_t)EpM * 4);
    ushort_t* xb     = (ushort_t*)take((size_t)n * 128 * 2);
    ushort_t* w1b    = (ushort_t*)take((size_t)272 * 128 * 2);   // 256 W1 rows + 16 wa rows
    ushort_t* w2b    = (ushort_t*)take((size_t)336 * 256 * 2);   // 320 W2 rows + 16 wa rows
    uchar_t*  h1f8   = (uchar_t*)take((size_t)(n + 1) * 256);
    ushort_t* helu   = (ushort_t*)take((size_t)n * 256 * 2);
    uchar_t*  h2f8   = (uchar_t*)take((size_t)(n + 1) * 320);
    float*    als1   = (float*)take((size_t)(n + 1) * 8 * 4);
    float*    ald1   = (float*)take((size_t)n * 8 * 4);
    float*    als2   = (float*)take((size_t)(n + 1) * 8 * 4);
    float*    ald2   = (float*)take((size_t)n * 8 * 4);

    hipMemsetAsync(deg, 0, (size_t)n * 4, stream);
    pad_row_kernel<<<1, 512, 0, stream>>>(als1, als2, h1f8, h2f8, n);

    // dtype converts + folded attention rows
    conv_kernel<<<2048, 256, 0, stream>>>(x, xb, n * 128 / 4);
    conv_kernel<<<32, 256, 0, stream>>>(W1, w1b, 256 * 128 / 4);
    conv_kernel<<<80, 256, 0, stream>>>(W2, w2b, 320 * 256 / 4);
    build_wa<128, 32><<<8, 256, 0, stream>>>(W1, a_src1, a_dst1, w1b, 256);
    build_wa<256, 40><<<16, 256, 0, stream>>>(W2, a_src2, a_dst2, w2b, 320);

    // CSR (8-padded rows)
    int eb = (Etot + 255) / 256;
    count_kernel<<<eb, 256, 0, stream>>>(ei, E, n, deg);
    scan_kernel<<<1, 1024, 0, stream>>>(deg, rowptr, cursor, n);
    scatter_kernel<<<eb, 256, 0, stream>>>(ei, E, n, cursor, ssrc);
    pad_fill_kernel<<<(n + 255) / 256, 256, 0, stream>>>(rowptr, cursor, ssrc, n);

    int gb = (n + 255) / 256;
    int nb4 = (n + 3) / 4;

    // layer 1 (gemm computes fp8 h1 AND f32 als1/ald1)
    gemm_lds_al<17, 128><<<gb, 512, 0, stream>>>(xb, w1b, h1f8, als1, ald1, n);
    agg1_kernel<<<nb4, 256, 0, stream>>>(h1f8, als1, ald1, b1, rowptr, ssrc, helu, n);

    // layer 2
    gemm_lds_al<21, 256><<<gb, 512, 0, stream>>>(helu, w2b, h2f8, als2, ald2, n);
    agg2_kernel<<<nb4, 256, 0, stream>>>(h2f8, als2, ald2, b2, rowptr, ssrc, out, n);
}

// Round 14
// 296.388 us; speedup vs baseline: 1.3800x; 1.0334x over previous
//
#include <hip/hip_runtime.h>
#include <hip/hip_bf16.h>
#include <math.h>

typedef unsigned short ushort_t;
typedef unsigned char uchar_t;
typedef __attribute__((ext_vector_type(8))) short short8;
typedef __attribute__((ext_vector_type(4))) float f32x4;
typedef __attribute__((ext_vector_type(2))) float f32x2;
typedef __attribute__((ext_vector_type(4))) unsigned short u16x4;

#define LOG2E 1.44269504088896f

static __device__ __forceinline__ float b2f(ushort_t u) {
    union { unsigned int i; float f; } v; v.i = ((unsigned int)u) << 16; return v.f;
}
static __device__ __forceinline__ ushort_t f2b(float f) {
    unsigned int x = __float_as_uint(f);
    unsigned int r = (x + 0x7fffu + ((x >> 16) & 1u)) >> 16;
    return (ushort_t)r;
}
static __device__ __forceinline__ uchar_t f2e4m3(float f) {
    int r = __builtin_amdgcn_cvt_pk_fp8_f32(f, f, 0, false);
    return (uchar_t)(r & 0xff);
}
static __device__ __forceinline__ float exp2fast(float x) {
    return __builtin_amdgcn_exp2f(x);     // v_exp_f32 (2^x)
}

// ---------------- merged prologue: conv W1/W2, build wa1/wa2, pad rows ----------------

template<int K, int Cd>
static __device__ void wa_item(const float* __restrict__ W, const float* __restrict__ as,
                               const float* __restrict__ ad, ushort_t* __restrict__ Bext,
                               int rowoff, int tid) {
    int col = tid / K, k = tid - col * K;
    const float* a = (col < 8) ? as : ad;
    int h = col & 7;
    float s = 0.f;
    #pragma unroll 4
    for (int c = 0; c < Cd; ++c)
        s += W[(size_t)(h * Cd + c) * K + k] * a[h * Cd + c];
    Bext[(size_t)(rowoff + col) * K + k] = f2b(s * LOG2E);
}

__global__ void prep_kernel(const float* __restrict__ W1, const float* __restrict__ W2,
                            const float* __restrict__ as1, const float* __restrict__ ad1,
                            const float* __restrict__ as2, const float* __restrict__ ad2,
                            ushort_t* __restrict__ w1b, ushort_t* __restrict__ w2b,
                            float* als1, float* als2, uchar_t* h1f8, uchar_t* h2f8, int n) {
    int b = blockIdx.x, t = threadIdx.x;
    if (b < 40) {                     // conv W1 (8192 f4) + W2 (20480 f4)
        for (int i = b * 256 + t; i < 8192 + 20480; i += 40 * 256) {
            if (i < 8192) {
                float4 v = *(const float4*)(W1 + i * 4);
                u16x4 o = { f2b(v.x), f2b(v.y), f2b(v.z), f2b(v.w) };
                *(u16x4*)(w1b + i * 4) = o;
            } else {
                int j = i - 8192;
                float4 v = *(const float4*)(W2 + j * 4);
                u16x4 o = { f2b(v.x), f2b(v.y), f2b(v.z), f2b(v.w) };
                *(u16x4*)(w2b + j * 4) = o;
            }
        }
    } else if (b < 64) {              // wa1 (2048 items) + wa2 (4096 items)
        for (int i = (b - 40) * 256 + t; i < 2048 + 4096; i += 24 * 256) {
            if (i < 2048) wa_item<128, 32>(W1, as1, ad1, w1b, 256, i);
            else          wa_item<256, 40>(W2, as2, ad2, w2b, 320, i - 2048);
        }
    } else {                          // pads (sentinel row n)
        if (t < 8) { als1[(size_t)n * 8 + t] = -1e30f; als2[(size_t)n * 8 + t] = -1e30f; }
        h1f8[(size_t)n * 256 + t] = 0;
        h2f8[(size_t)n * 320 + t] = 0;
        if (t < 64) h2f8[(size_t)n * 320 + 256 + t] = 0;
    }
}

// ---------------- merged conv_x + degree count ----------------

__global__ void convx_count_kernel(const float* __restrict__ x, ushort_t* __restrict__ xb, int n4x,
                                   const int* __restrict__ ei, int E, int n, int* __restrict__ deg) {
    int b = blockIdx.x, t = threadIdx.x;
    if (b < 2048) {
        for (int i = b * 256 + t; i < n4x; i += 2048 * 256) {
            float4 v = *(const float4*)(x + i * 4);
            u16x4 o = { f2b(v.x), f2b(v.y), f2b(v.z), f2b(v.w) };
            *(u16x4*)(xb + i * 4) = o;
        }
    } else {
        int e = (b - 2048) * 256 + t;
        int Etot = E + n;
        if (e < Etot) {
            int dst = (e < E) ? ei[E + e] : (e - E);
            atomicAdd(&deg[dst], 1);
        }
    }
}

// ---------------- CSR build (rows padded to multiples of 8) ----------------

__global__ void scan_kernel(const int* __restrict__ deg, int* __restrict__ rowptr,
                            int* __restrict__ cursor, int n) {
    __shared__ int wsum[16];
    int t = threadIdx.x;
    int lane = t & 63, wid = t >> 6;
    int carry = 0;
    for (int base = 0; base < n; base += 1024) {
        int i = base + t;
        int v = (i < n) ? ((deg[i] + 7) & ~7) : 0;   // padded degree
        int val = v;
        #pragma unroll
        for (int off = 1; off < 64; off <<= 1) {
            int nv = __shfl_up(val, off);
            if (lane >= off) val += nv;
        }
        if (lane == 63) wsum[wid] = val;
        __syncthreads();
        int wpre = 0, tot = 0;
        #pragma unroll
        for (int w = 0; w < 16; ++w) {
            int s = wsum[w];
            if (w < wid) wpre += s;
            tot += s;
        }
        int excl = carry + wpre + val - v;
        if (i < n) { rowptr[i] = excl; cursor[i] = excl; }
        carry += tot;
        __syncthreads();
    }
    if (t == 0) rowptr[n] = carry;
}

__global__ void scatter_kernel(const int* __restrict__ ei, int E, int n,
                               int* __restrict__ cursor, int* __restrict__ ssrc) {
    int e = blockIdx.x * blockDim.x + threadIdx.x;
    int Etot = E + n;
    if (e >= Etot) return;
    int src, dst;
    if (e < E) { src = ei[e]; dst = ei[E + e]; }
    else       { src = e - E; dst = e - E; }
    int pos = atomicAdd(&cursor[dst], 1);
    ssrc[pos] = src;
}

__global__ void pad_fill_kernel(const int* __restrict__ rowptr, const int* __restrict__ cursor,
                                int* __restrict__ ssrc, int n) {
    int i = blockIdx.x * blockDim.x + threadIdx.x;
    if (i >= n) return;
    int p = cursor[i], e = rowptr[i + 1];
    for (; p < e; ++p) ssrc[p] = n;   // sentinel
}

// ---------------- bf16 MFMA NT GEMM + fused attention logits, fp8 feature output ----------------
// BM = 128 (8 waves x 16 rows), single accumulator set (R11 known-good config).

template<int NFRAG, int K>
__global__ __launch_bounds__(512) void gemm_lds_al(const ushort_t* __restrict__ A,
                                                   const ushort_t* __restrict__ B,
                                                   uchar_t* __restrict__ C,
                                                   float* __restrict__ als,
                                                   float* __restrict__ ald, int M) {
    constexpr int N = NFRAG * 16;
    constexpr int NOUT = (NFRAG - 1) * 16;
    constexpr int RS = 40;                 // LDS row stride in elems
    constexpr int NK = K / 32;
    __shared__ ushort_t Bs[2][N * RS];
    const int t = threadIdx.x;
    const int w = t >> 6, l = t & 63;
    const int r0 = blockIdx.x * 128 + w * 16;
    int arow = r0 + (l & 15);
    if (arow >= M) arow = M - 1;
    const int koff = (l >> 4) * 8;
    const ushort_t* ap = A + (size_t)arow * K + koff;

    f32x4 acc[NFRAG];
    #pragma unroll
    for (int i = 0; i < NFRAG; ++i) acc[i] = (f32x4){0.f, 0.f, 0.f, 0.f};

    auto stage = [&](int buf, int k0) {
        #pragma unroll
        for (int c = t; c < N * 4; c += 512) {
            int row = c >> 2, part = (c & 3) << 3;           // part in elems
            *(short8*)&Bs[buf][row * RS + part] =
                *(const short8*)(B + (size_t)row * K + k0 + part);
        }
    };

    stage(0, 0);
    __syncthreads();
    #pragma unroll
    for (int kk = 0; kk < NK; ++kk) {
        int buf = kk & 1;
        if (kk + 1 < NK) stage(buf ^ 1, (kk + 1) * 32);
        short8 a = *(const short8*)(ap + kk * 32);
        #pragma unroll
        for (int nf = 0; nf < NFRAG; ++nf) {
            short8 b = *(const short8*)&Bs[buf][(nf * 16 + (l & 15)) * RS + koff];
            acc[nf] = __builtin_amdgcn_mfma_f32_16x16x32_bf16(a, b, acc[nf], 0, 0, 0);
        }
        __syncthreads();
    }

    const int crow0 = r0 + (l >> 4) * 4;
    #pragma unroll
    for (int nf = 0; nf < NFRAG - 1; ++nf) {
        #pragma unroll
        for (int j = 0; j < 4; ++j) {
            int row = crow0 + j;
            if (row < M) C[(size_t)row * NOUT + nf * 16 + (l & 15)] = f2e4m3(acc[nf][j]);
        }
    }
    {   // attention-logit fragment (pre-scaled by log2e)
        int col = l & 15;
        float* dstp = (col < 8) ? als : ald;
        int h = col & 7;
        #pragma unroll
        for (int j = 0; j < 4; ++j) {
            int row = crow0 + j;
            if (row < M) dstp[(size_t)row * 8 + h] = acc[NFRAG - 1][j];
        }
    }
}

// ---------------- layer-1 aggregation: 8-edge unrolled, no-max exp2 softmax, fp8 gather ----------------

__device__ __forceinline__ float lrelu(float e) { return (e > 0.f) ? e : 0.2f * e; }

__global__ void agg1_kernel(const uchar_t* __restrict__ h1, const float* __restrict__ als,
                            const float* __restrict__ aldv, const float* __restrict__ b1,
                            const int* __restrict__ rowptr, const int* __restrict__ ssrc,
                            ushort_t* __restrict__ hout, int n) {
    int node = blockIdx.x * 4 + (threadIdx.x >> 6);
    if (node >= n) return;
    int l = threadIdx.x & 63;
    int h = l >> 3;
    float ald = aldv[node * 8 + h];
    int beg = rowptr[node], end = rowptr[node + 1];
    float den = 0.f, a0 = 0.f, a1 = 0.f, a2 = 0.f, a3 = 0.f;
    for (int p = beg; p < end; p += 8) {
        int4 sA = *(const int4*)(ssrc + p);
        int4 sB = *(const int4*)(ssrc + p + 4);
        float w0 = exp2fast(lrelu(als[sA.x * 8 + h] + ald));
        float w1 = exp2fast(lrelu(als[sA.y * 8 + h] + ald));
        float w2 = exp2fast(lrelu(als[sA.z * 8 + h] + ald));
        float w3 = exp2fast(lrelu(als[sA.w * 8 + h] + ald));
        float w4 = exp2fast(lrelu(als[sB.x * 8 + h] + ald));
        float w5 = exp2fast(lrelu(als[sB.y * 8 + h] + ald));
        float w6 = exp2fast(lrelu(als[sB.z * 8 + h] + ald));
        float w7 = exp2fast(lrelu(als[sB.w * 8 + h] + ald));
        int g0 = *(const int*)(h1 + (size_t)sA.x * 256 + l * 4);
        int g1 = *(const int*)(h1 + (size_t)sA.y * 256 + l * 4);
        int g2 = *(const int*)(h1 + (size_t)sA.z * 256 + l * 4);
        int g3 = *(const int*)(h1 + (size_t)sA.w * 256 + l * 4);
        int g4 = *(const int*)(h1 + (size_t)sB.x * 256 + l * 4);
        int g5 = *(const int*)(h1 + (size_t)sB.y * 256 + l * 4);
        int g6 = *(const int*)(h1 + (size_t)sB.z * 256 + l * 4);
        int g7 = *(const int*)(h1 + (size_t)sB.w * 256 + l * 4);
        den += ((w0 + w1) + (w2 + w3)) + ((w4 + w5) + (w6 + w7));
        #define DQ(g, wv) { \
            f32x2 lo = __builtin_amdgcn_cvt_pk_f32_fp8(g, false); \
            f32x2 hi = __builtin_amdgcn_cvt_pk_f32_fp8(g, true);  \
            a0 += wv * lo.x; a1 += wv * lo.y; a2 += wv * hi.x; a3 += wv * hi.y; }
        DQ(g0, w0) DQ(g1, w1) DQ(g2, w2) DQ(g3, w3)
        DQ(g4, w4) DQ(g5, w5) DQ(g6, w6) DQ(g7, w7)
        #undef DQ
    }
    float inv = 1.f / den;
    float4 bv = *(const float4*)(b1 + l * 4);
    float v0 = a0 * inv + bv.x, v1 = a1 * inv + bv.y;
    float v2 = a2 * inv + bv.z, v3 = a3 * inv + bv.w;
    u16x4 o;
    o.x = f2b((v0 > 0.f) ? v0 : __expf(v0) - 1.f);
    o.y = f2b((v1 > 0.f) ? v1 : __expf(v1) - 1.f);
    o.z = f2b((v2 > 0.f) ? v2 : __expf(v2) - 1.f);
    o.w = f2b((v3 > 0.f) ? v3 : __expf(v3) - 1.f);
    *(u16x4*)(hout + (size_t)node * 256 + l * 4) = o;
}

// ---------------- layer-2 aggregation: 8-edge unrolled fp8 gather + head-mean + log_softmax ----------------

__global__ void agg2_kernel(const uchar_t* __restrict__ h2, const float* __restrict__ als,
                            const float* __restrict__ aldv, const float* __restrict__ b2,
                            const int* __restrict__ rowptr, const int* __restrict__ ssrc,
                            float* __restrict__ out, int n) {
    int node = blockIdx.x * 4 + (threadIdx.x >> 6);
    if (node >= n) return;
    int l = threadIdx.x & 63;
    int li = (l < 40) ? l : 0;
    int hd = li / 5;
    int cg = li - hd * 5;
    float ald = aldv[node * 8 + hd];
    int beg = rowptr[node], end = rowptr[node + 1];
    const uchar_t* base = h2 + hd * 40 + cg * 8;
    float den = 0.f;
    float a0 = 0.f, a1 = 0.f, a2 = 0.f, a3 = 0.f, a4 = 0.f, a5 = 0.f, a6 = 0.f, a7 = 0.f;
    for (int p = beg; p < end; p += 8) {
        int4 sA = *(const int4*)(ssrc + p);
        int4 sB = *(const int4*)(ssrc + p + 4);
        float w0 = exp2fast(lrelu(als[sA.x * 8 + hd] + ald));
        float w1 = exp2fast(lrelu(als[sA.y * 8 + hd] + ald));
        float w2 = exp2fast(lrelu(als[sA.z * 8 + hd] + ald));
        float w3 = exp2fast(lrelu(als[sA.w * 8 + hd] + ald));
        float w4 = exp2fast(lrelu(als[sB.x * 8 + hd] + ald));
        float w5 = exp2fast(lrelu(als[sB.y * 8 + hd] + ald));
        float w6 = exp2fast(lrelu(als[sB.z * 8 + hd] + ald));
        float w7 = exp2fast(lrelu(als[sB.w * 8 + hd] + ald));
        uint2 g0 = *(const uint2*)(base + (size_t)sA.x * 320);
        uint2 g1 = *(const uint2*)(base + (size_t)sA.y * 320);
        uint2 g2 = *(const uint2*)(base + (size_t)sA.z * 320);
        uint2 g3 = *(const uint2*)(base + (size_t)sA.w * 320);
        uint2 g4 = *(const uint2*)(base + (size_t)sB.x * 320);
        uint2 g5 = *(const uint2*)(base + (size_t)sB.y * 320);
        uint2 g6 = *(const uint2*)(base + (size_t)sB.z * 320);
        uint2 g7 = *(const uint2*)(base + (size_t)sB.w * 320);
        den += ((w0 + w1) + (w2 + w3)) + ((w4 + w5) + (w6 + w7));
        #define DQ(g, wv) { \
            f32x2 q0 = __builtin_amdgcn_cvt_pk_f32_fp8((int)g.x, false); \
            f32x2 q1 = __builtin_amdgcn_cvt_pk_f32_fp8((int)g.x, true);  \
            f32x2 q2 = __builtin_amdgcn_cvt_pk_f32_fp8((int)g.y, false); \
            f32x2 q3 = __builtin_amdgcn_cvt_pk_f32_fp8((int)g.y, true);  \
            a0 += wv * q0.x; a1 += wv * q0.y; a2 += wv * q1.x; a3 += wv * q1.y; \
            a4 += wv * q2.x; a5 += wv * q2.y; a6 += wv * q3.x; a7 += wv * q3.y; }
        DQ(g0, w0) DQ(g1, w1) DQ(g2, w2) DQ(g3, w3)
        DQ(g4, w4) DQ(g5, w5) DQ(g6, w6) DQ(g7, w7)
        #undef DQ
    }
    float inv = 1.f / den;
    float v[8] = {a0 * inv, a1 * inv, a2 * inv, a3 * inv,
                  a4 * inv, a5 * inv, a6 * inv, a7 * inv};
    #pragma unroll
    for (int j = 0; j < 8; ++j) {
        float s = v[j];
        s += __shfl_down(s, 20);
        s += __shfl_down(s, 10);
        s += __shfl_down(s, 5);
        v[j] = s;
    }
    if (l < 5) {
        float wv[8];
        #pragma unroll
        for (int j = 0; j < 8; ++j) wv[j] = 0.125f * v[j] + b2[l * 8 + j];
        float m8 = wv[0];
        #pragma unroll
        for (int j = 1; j < 8; ++j) m8 = fmaxf(m8, wv[j]);
        float mx = m8;
        #pragma unroll
        for (int k = 0; k < 5; ++k) mx = fmaxf(mx, __shfl(m8, k));
        float se8 = 0.f;
        #pragma unroll
        for (int j = 0; j < 8; ++j) se8 += __expf(wv[j] - mx);
        float se = 0.f;
        #pragma unroll
        for (int k = 0; k < 5; ++k) se += __shfl(se8, k);
        float lse = mx + __logf(se);
        float* op = out + (size_t)node * 40 + l * 8;
        float4 o0 = {wv[0] - lse, wv[1] - lse, wv[2] - lse, wv[3] - lse};
        float4 o1 = {wv[4] - lse, wv[5] - lse, wv[6] - lse, wv[7] - lse};
        *(float4*)op = o0;
        *(float4*)(op + 4) = o1;
    }
}

// ---------------- launch ----------------

extern "C" void kernel_launch(void* const* d_in, const int* in_sizes, int n_in,
                              void* d_out, int out_size, void* d_ws, size_t ws_size,
                              hipStream_t stream) {
    const float* x      = (const float*)d_in[0];
    const int*   ei     = (const int*)d_in[1];
    const float* W1     = (const float*)d_in[2];
    const float* a_src1 = (const float*)d_in[3];
    const float* a_dst1 = (const float*)d_in[4];
    const float* b1     = (const float*)d_in[5];
    const float* W2     = (const float*)d_in[6];
    const float* a_src2 = (const float*)d_in[7];
    const float* a_dst2 = (const float*)d_in[8];
    const float* b2     = (const float*)d_in[9];
    float* out = (float*)d_out;

    const int n    = in_sizes[0] / 128;   // 50000
    const int E    = in_sizes[1] / 2;     // 800000
    const int Etot = E + n;
    const int EpM  = Etot + 7 * n + 16;   // upper bound on padded edge count

    char* w = (char*)d_ws;
    auto take = [&](size_t bytes) {
        char* p = w;
        w += (bytes + 255) & ~(size_t)255;
        return p;
    };
    int*      deg    = (int*)take((size_t)n * 4);
    int*      rowptr = (int*)take((size_t)(n + 1) * 4);
    int*      cursor = (int*)take((size_t)n * 4);
    int*      ssrc   = (int*)take((size_t)EpM * 4);
    ushort_t* xb     = (ushort_t*)take((size_t)n * 128 * 2);
    ushort_t* w1b    = (ushort_t*)take((size_t)272 * 128 * 2);   // 256 W1 rows + 16 wa rows
    ushort_t* w2b    = (ushort_t*)take((size_t)336 * 256 * 2);   // 320 W2 rows + 16 wa rows
    uchar_t*  h1f8   = (uchar_t*)take((size_t)(n + 1) * 256);
    ushort_t* helu   = (ushort_t*)take((size_t)n * 256 * 2);
    uchar_t*  h2f8   = (uchar_t*)take((size_t)(n + 1) * 320);
    float*    als1   = (float*)take((size_t)(n + 1) * 8 * 4);
    float*    ald1   = (float*)take((size_t)n * 8 * 4);
    float*    als2   = (float*)take((size_t)(n + 1) * 8 * 4);
    float*    ald2   = (float*)take((size_t)n * 8 * 4);

    hipMemsetAsync(deg, 0, (size_t)n * 4, stream);

    // merged prologue (W converts + wa folds + sentinel pads)
    prep_kernel<<<65, 256, 0, stream>>>(W1, W2, a_src1, a_dst1, a_src2, a_dst2,
                                        w1b, w2b, als1, als2, h1f8, h2f8, n);

    // merged x-convert + degree count, then CSR
    int eb = (Etot + 255) / 256;
    convx_count_kernel<<<2048 + eb, 256, 0, stream>>>(x, xb, n * 128 / 4, ei, E, n, deg);
    scan_kernel<<<1, 1024, 0, stream>>>(deg, rowptr, cursor, n);
    scatter_kernel<<<eb, 256, 0, stream>>>(ei, E, n, cursor, ssrc);
    pad_fill_kernel<<<(n + 255) / 256, 256, 0, stream>>>(rowptr, cursor, ssrc, n);

    int gb = (n + 127) / 128;
    int nb4 = (n + 3) / 4;

    // layer 1 (gemm computes fp8 h1 AND f32 als1/ald1)
    gemm_lds_al<17, 128><<<gb, 512, 0, stream>>>(xb, w1b, h1f8, als1, ald1, n);
    agg1_kernel<<<nb4, 256, 0, stream>>>(h1f8, als1, ald1, b1, rowptr, ssrc, helu, n);

    // layer 2
    gemm_lds_al<21, 256><<<gb, 512, 0, stream>>>(helu, w2b, h2f8, als2, ald2, n);
    agg2_kernel<<<nb4, 256, 0, stream>>>(h2f8, als2, ald2, b2, rowptr, ssrc, out, n);
}

// Round 16
// 258.177 us; speedup vs baseline: 1.5842x; 1.1480x over previous
//
#include <hip/hip_runtime.h>
#include <hip/hip_bf16.h>
#include <math.h>

typedef unsigned short ushort_t;
typedef unsigned char uchar_t;
typedef __attribute__((ext_vector_type(8))) short short8;
typedef __attribute__((ext_vector_type(4))) float f32x4;
typedef __attribute__((ext_vector_type(2))) float f32x2;
typedef __attribute__((ext_vector_type(4))) unsigned short u16x4;

#define LOG2E 1.44269504088896f

static __device__ __forceinline__ float b2f(ushort_t u) {
    union { unsigned int i; float f; } v; v.i = ((unsigned int)u) << 16; return v.f;
}
static __device__ __forceinline__ ushort_t f2b(float f) {
    unsigned int x = __float_as_uint(f);
    unsigned int r = (x + 0x7fffu + ((x >> 16) & 1u)) >> 16;
    return (ushort_t)r;
}
static __device__ __forceinline__ uchar_t f2e4m3(float f) {
    int r = __builtin_amdgcn_cvt_pk_fp8_f32(f, f, 0, false);
    return (uchar_t)(r & 0xff);
}
static __device__ __forceinline__ float exp2fast(float x) {
    return __builtin_amdgcn_exp2f(x);     // v_exp_f32 (2^x)
}

// ---------------- merged prologue: conv W1/W2, build wa1/wa2, pad rows ----------------

template<int K, int Cd>
static __device__ void wa_item(const float* __restrict__ W, const float* __restrict__ as,
                               const float* __restrict__ ad, ushort_t* __restrict__ Bext,
                               int rowoff, int tid) {
    int col = tid / K, k = tid - col * K;
    const float* a = (col < 8) ? as : ad;
    int h = col & 7;
    float s = 0.f;
    #pragma unroll 4
    for (int c = 0; c < Cd; ++c)
        s += W[(size_t)(h * Cd + c) * K + k] * a[h * Cd + c];
    Bext[(size_t)(rowoff + col) * K + k] = f2b(s * LOG2E);
}

__global__ void prep_kernel(const float* __restrict__ W1, const float* __restrict__ W2,
                            const float* __restrict__ as1, const float* __restrict__ ad1,
                            const float* __restrict__ as2, const float* __restrict__ ad2,
                            ushort_t* __restrict__ w1b, ushort_t* __restrict__ w2b,
                            float* als1, float* als2, uchar_t* h1f8, uchar_t* h2f8, int n) {
    int b = blockIdx.x, t = threadIdx.x;
    if (b < 40) {                     // conv W1 (8192 f4) + W2 (20480 f4)
        for (int i = b * 256 + t; i < 8192 + 20480; i += 40 * 256) {
            if (i < 8192) {
                float4 v = *(const float4*)(W1 + i * 4);
                u16x4 o = { f2b(v.x), f2b(v.y), f2b(v.z), f2b(v.w) };
                *(u16x4*)(w1b + i * 4) = o;
            } else {
                int j = i - 8192;
                float4 v = *(const float4*)(W2 + j * 4);
                u16x4 o = { f2b(v.x), f2b(v.y), f2b(v.z), f2b(v.w) };
                *(u16x4*)(w2b + j * 4) = o;
            }
        }
    } else if (b < 64) {              // wa1 (2048 items) + wa2 (4096 items)
        for (int i = (b - 40) * 256 + t; i < 2048 + 4096; i += 24 * 256) {
            if (i < 2048) wa_item<128, 32>(W1, as1, ad1, w1b, 256, i);
            else          wa_item<256, 40>(W2, as2, ad2, w2b, 320, i - 2048);
        }
    } else {                          // pads (sentinel row n)
        if (t < 8) { als1[(size_t)n * 8 + t] = -1e30f; als2[(size_t)n * 8 + t] = -1e30f; }
        h1f8[(size_t)n * 256 + t] = 0;
        h2f8[(size_t)n * 320 + t] = 0;
        if (t < 64) h2f8[(size_t)n * 320 + 256 + t] = 0;
    }
}

// ---------------- merged conv_x + degree count ----------------

__global__ void convx_count_kernel(const float* __restrict__ x, ushort_t* __restrict__ xb, int n4x,
                                   const int* __restrict__ ei, int E, int n, int* __restrict__ deg) {
    int b = blockIdx.x, t = threadIdx.x;
    if (b < 2048) {
        for (int i = b * 256 + t; i < n4x; i += 2048 * 256) {
            float4 v = *(const float4*)(x + i * 4);
            u16x4 o = { f2b(v.x), f2b(v.y), f2b(v.z), f2b(v.w) };
            *(u16x4*)(xb + i * 4) = o;
        }
    } else {
        int e = (b - 2048) * 256 + t;
        int Etot = E + n;
        if (e < Etot) {
            int dst = (e < E) ? ei[E + e] : (e - E);
            atomicAdd(&deg[dst], 1);
        }
    }
}

// ---------------- CSR build: 3-phase parallel scan (rows padded to multiples of 8) ----------------

__global__ void scan_part_kernel(const int* __restrict__ deg, int* __restrict__ bsum, int n) {
    int i = blockIdx.x * 256 + threadIdx.x;
    int v = (i < n) ? ((deg[i] + 7) & ~7) : 0;
    #pragma unroll
    for (int off = 1; off < 64; off <<= 1) v += __shfl_xor(v, off);
    __shared__ int ws[4];
    int wid = threadIdx.x >> 6, lane = threadIdx.x & 63;
    if (lane == 0) ws[wid] = v;
    __syncthreads();
    if (threadIdx.x == 0) bsum[blockIdx.x] = ws[0] + ws[1] + ws[2] + ws[3];
}

__global__ void scan_top_kernel(int* __restrict__ bsum, int nb) {
    int t = threadIdx.x;
    int v = (t < nb) ? bsum[t] : 0;
    int val = v;
    int lane = t & 63, wid = t >> 6;
    #pragma unroll
    for (int off = 1; off < 64; off <<= 1) {
        int nv = __shfl_up(val, off);
        if (lane >= off) val += nv;
    }
    __shared__ int ws[4];
    if (lane == 63) ws[wid] = val;
    __syncthreads();
    int pre = 0;
    for (int w = 0; w < 4; ++w) if (w < wid) pre += ws[w];
    if (t < nb) bsum[t] = pre + val - v;
}

__global__ void scan_write_kernel(const int* __restrict__ deg, const int* __restrict__ bsum,
                                  int* __restrict__ rowptr, int* __restrict__ cursor, int n) {
    int i = blockIdx.x * 256 + threadIdx.x;
    int t = threadIdx.x;
    int v = (i < n) ? ((deg[i] + 7) & ~7) : 0;
    int val = v;
    int lane = t & 63, wid = t >> 6;
    #pragma unroll
    for (int off = 1; off < 64; off <<= 1) {
        int nv = __shfl_up(val, off);
        if (lane >= off) val += nv;
    }
    __shared__ int ws[4];
    if (lane == 63) ws[wid] = val;
    __syncthreads();
    int pre = bsum[blockIdx.x];
    for (int w = 0; w < 4; ++w) if (w < wid) pre += ws[w];
    int excl = pre + val - v;
    if (i < n) { rowptr[i] = excl; cursor[i] = excl; }
    if (i == n - 1) rowptr[n] = excl + v;
}

__global__ void scatter_kernel(const int* __restrict__ ei, int E, int n,
                               int* __restrict__ cursor, int* __restrict__ ssrc) {
    int e = blockIdx.x * blockDim.x + threadIdx.x;
    int Etot = E + n;
    if (e >= Etot) return;
    int src, dst;
    if (e < E) { src = ei[e]; dst = ei[E + e]; }
    else       { src = e - E; dst = e - E; }
    int pos = atomicAdd(&cursor[dst], 1);
    ssrc[pos] = src;
}

__global__ void pad_fill_kernel(const int* __restrict__ rowptr, const int* __restrict__ cursor,
                                int* __restrict__ ssrc, int n) {
    int i = blockIdx.x * blockDim.x + threadIdx.x;
    if (i >= n) return;
    int p = cursor[i], e = rowptr[i + 1];
    for (; p < e; ++p) ssrc[p] = n;   // sentinel
}

// ---------------- bf16 MFMA NT GEMM + fused attention logits, fp8 feature output ----------------
// BM = 128 (8 waves x 16 rows), single accumulator set (known-good config).

template<int NFRAG, int K>
__global__ __launch_bounds__(512) void gemm_lds_al(const ushort_t* __restrict__ A,
                                                   const ushort_t* __restrict__ B,
                                                   uchar_t* __restrict__ C,
                                                   float* __restrict__ als,
                                                   float* __restrict__ ald, int M) {
    constexpr int N = NFRAG * 16;
    constexpr int NOUT = (NFRAG - 1) * 16;
    constexpr int RS = 40;                 // LDS row stride in elems
    constexpr int NK = K / 32;
    __shared__ ushort_t Bs[2][N * RS];
    const int t = threadIdx.x;
    const int w = t >> 6, l = t & 63;
    const int r0 = blockIdx.x * 128 + w * 16;
    int arow = r0 + (l & 15);
    if (arow >= M) arow = M - 1;
    const int koff = (l >> 4) * 8;
    const ushort_t* ap = A + (size_t)arow * K + koff;

    f32x4 acc[NFRAG];
    #pragma unroll
    for (int i = 0; i < NFRAG; ++i) acc[i] = (f32x4){0.f, 0.f, 0.f, 0.f};

    auto stage = [&](int buf, int k0) {
        #pragma unroll
        for (int c = t; c < N * 4; c += 512) {
            int row = c >> 2, part = (c & 3) << 3;           // part in elems
            *(short8*)&Bs[buf][row * RS + part] =
                *(const short8*)(B + (size_t)row * K + k0 + part);
        }
    };

    stage(0, 0);
    __syncthreads();
    #pragma unroll
    for (int kk = 0; kk < NK; ++kk) {
        int buf = kk & 1;
        if (kk + 1 < NK) stage(buf ^ 1, (kk + 1) * 32);
        short8 a = *(const short8*)(ap + kk * 32);
        #pragma unroll
        for (int nf = 0; nf < NFRAG; ++nf) {
            short8 b = *(const short8*)&Bs[buf][(nf * 16 + (l & 15)) * RS + koff];
            acc[nf] = __builtin_amdgcn_mfma_f32_16x16x32_bf16(a, b, acc[nf], 0, 0, 0);
        }
        __syncthreads();
    }

    const int crow0 = r0 + (l >> 4) * 4;
    #pragma unroll
    for (int nf = 0; nf < NFRAG - 1; ++nf) {
        #pragma unroll
        for (int j = 0; j < 4; ++j) {
            int row = crow0 + j;
            if (row < M) C[(size_t)row * NOUT + nf * 16 + (l & 15)] = f2e4m3(acc[nf][j]);
        }
    }
    {   // attention-logit fragment (pre-scaled by log2e)
        int col = l & 15;
        float* dstp = (col < 8) ? als : ald;
        int h = col & 7;
        #pragma unroll
        for (int j = 0; j < 4; ++j) {
            int row = crow0 + j;
            if (row < M) dstp[(size_t)row * 8 + h] = acc[NFRAG - 1][j];
        }
    }
}

// ---------------- layer-1 aggregation: 8-edge unrolled, packed f32x2 FMA, fp8 gather ----------------

__device__ __forceinline__ float lrelu(float e) { return (e > 0.f) ? e : 0.2f * e; }

__global__ void agg1_kernel(const uchar_t* __restrict__ h1, const float* __restrict__ als,
                            const float* __restrict__ aldv, const float* __restrict__ b1,
                            const int* __restrict__ rowptr, const int* __restrict__ ssrc,
                            ushort_t* __restrict__ hout, int n) {
    int node = blockIdx.x * 4 + (threadIdx.x >> 6);
    if (node >= n) return;
    int l = threadIdx.x & 63;
    int h = l >> 3;
    float ald = aldv[node * 8 + h];
    int beg = rowptr[node], end = rowptr[node + 1];
    float den = 0.f;
    f32x2 acc01 = {0.f, 0.f}, acc23 = {0.f, 0.f};
    for (int p = beg; p < end; p += 8) {
        int4 sA = *(const int4*)(ssrc + p);
        int4 sB = *(const int4*)(ssrc + p + 4);
        float w0 = exp2fast(lrelu(als[sA.x * 8 + h] + ald));
        float w1 = exp2fast(lrelu(als[sA.y * 8 + h] + ald));
        float w2 = exp2fast(lrelu(als[sA.z * 8 + h] + ald));
        float w3 = exp2fast(lrelu(als[sA.w * 8 + h] + ald));
        float w4 = exp2fast(lrelu(als[sB.x * 8 + h] + ald));
        float w5 = exp2fast(lrelu(als[sB.y * 8 + h] + ald));
        float w6 = exp2fast(lrelu(als[sB.z * 8 + h] + ald));
        float w7 = exp2fast(lrelu(als[sB.w * 8 + h] + ald));
        int g0 = *(const int*)(h1 + (size_t)sA.x * 256 + l * 4);
        int g1 = *(const int*)(h1 + (size_t)sA.y * 256 + l * 4);
        int g2 = *(const int*)(h1 + (size_t)sA.z * 256 + l * 4);
        int g3 = *(const int*)(h1 + (size_t)sA.w * 256 + l * 4);
        int g4 = *(const int*)(h1 + (size_t)sB.x * 256 + l * 4);
        int g5 = *(const int*)(h1 + (size_t)sB.y * 256 + l * 4);
        int g6 = *(const int*)(h1 + (size_t)sB.z * 256 + l * 4);
        int g7 = *(const int*)(h1 + (size_t)sB.w * 256 + l * 4);
        den += ((w0 + w1) + (w2 + w3)) + ((w4 + w5) + (w6 + w7));
        #define DQ(g, wv) { \
            f32x2 lo = __builtin_amdgcn_cvt_pk_f32_fp8(g, false); \
            f32x2 hi = __builtin_amdgcn_cvt_pk_f32_fp8(g, true);  \
            f32x2 w2v = {wv, wv}; \
            acc01 += w2v * lo; acc23 += w2v * hi; }
        DQ(g0, w0) DQ(g1, w1) DQ(g2, w2) DQ(g3, w3)
        DQ(g4, w4) DQ(g5, w5) DQ(g6, w6) DQ(g7, w7)
        #undef DQ
    }
    float inv = 1.f / den;
    float4 bv = *(const float4*)(b1 + l * 4);
    float v0 = acc01.x * inv + bv.x, v1 = acc01.y * inv + bv.y;
    float v2 = acc23.x * inv + bv.z, v3 = acc23.y * inv + bv.w;
    u16x4 o;
    o.x = f2b((v0 > 0.f) ? v0 : __expf(v0) - 1.f);
    o.y = f2b((v1 > 0.f) ? v1 : __expf(v1) - 1.f);
    o.z = f2b((v2 > 0.f) ? v2 : __expf(v2) - 1.f);
    o.w = f2b((v3 > 0.f) ? v3 : __expf(v3) - 1.f);
    *(u16x4*)(hout + (size_t)node * 256 + l * 4) = o;
}

// ---------------- layer-2 aggregation: 8-edge unrolled, packed f32x2 FMA + head-mean + log_softmax ----------------

__global__ void agg2_kernel(const uchar_t* __restrict__ h2, const float* __restrict__ als,
                            const float* __restrict__ aldv, const float* __restrict__ b2,
                            const int* __restrict__ rowptr, const int* __restrict__ ssrc,
                            float* __restrict__ out, int n) {
    int node = blockIdx.x * 4 + (threadIdx.x >> 6);
    if (node >= n) return;
    int l = threadIdx.x & 63;
    int li = (l < 40) ? l : 0;
    int hd = li / 5;
    int cg = li - hd * 5;
    float ald = aldv[node * 8 + hd];
    int beg = rowptr[node], end = rowptr[node + 1];
    const uchar_t* base = h2 + hd * 40 + cg * 8;
    float den = 0.f;
    f32x2 acc01 = {0.f, 0.f}, acc23 = {0.f, 0.f}, acc45 = {0.f, 0.f}, acc67 = {0.f, 0.f};
    for (int p = beg; p < end; p += 8) {
        int4 sA = *(const int4*)(ssrc + p);
        int4 sB = *(const int4*)(ssrc + p + 4);
        float w0 = exp2fast(lrelu(als[sA.x * 8 + hd] + ald));
        float w1 = exp2fast(lrelu(als[sA.y * 8 + hd] + ald));
        float w2 = exp2fast(lrelu(als[sA.z * 8 + hd] + ald));
        float w3 = exp2fast(lrelu(als[sA.w * 8 + hd] + ald));
        float w4 = exp2fast(lrelu(als[sB.x * 8 + hd] + ald));
        float w5 = exp2fast(lrelu(als[sB.y * 8 + hd] + ald));
        float w6 = exp2fast(lrelu(als[sB.z * 8 + hd] + ald));
        float w7 = exp2fast(lrelu(als[sB.w * 8 + hd] + ald));
        uint2 g0 = *(const uint2*)(base + (size_t)sA.x * 320);
        uint2 g1 = *(const uint2*)(base + (size_t)sA.y * 320);
        uint2 g2 = *(const uint2*)(base + (size_t)sA.z * 320);
        uint2 g3 = *(const uint2*)(base + (size_t)sA.w * 320);
        uint2 g4 = *(const uint2*)(base + (size_t)sB.x * 320);
        uint2 g5 = *(const uint2*)(base + (size_t)sB.y * 320);
        uint2 g6 = *(const uint2*)(base + (size_t)sB.z * 320);
        uint2 g7 = *(const uint2*)(base + (size_t)sB.w * 320);
        den += ((w0 + w1) + (w2 + w3)) + ((w4 + w5) + (w6 + w7));
        #define DQ(g, wv) { \
            f32x2 q0 = __builtin_amdgcn_cvt_pk_f32_fp8((int)g.x, false); \
            f32x2 q1 = __builtin_amdgcn_cvt_pk_f32_fp8((int)g.x, true);  \
            f32x2 q2 = __builtin_amdgcn_cvt_pk_f32_fp8((int)g.y, false); \
            f32x2 q3 = __builtin_amdgcn_cvt_pk_f32_fp8((int)g.y, true);  \
            f32x2 w2v = {wv, wv}; \
            acc01 += w2v * q0; acc23 += w2v * q1; \
            acc45 += w2v * q2; acc67 += w2v * q3; }
        DQ(g0, w0) DQ(g1, w1) DQ(g2, w2) DQ(g3, w3)
        DQ(g4, w4) DQ(g5, w5) DQ(g6, w6) DQ(g7, w7)
        #undef DQ
    }
    float inv = 1.f / den;
    float v[8] = {acc01.x * inv, acc01.y * inv, acc23.x * inv, acc23.y * inv,
                  acc45.x * inv, acc45.y * inv, acc67.x * inv, acc67.y * inv};
    #pragma unroll
    for (int j = 0; j < 8; ++j) {
        float s = v[j];
        s += __shfl_down(s, 20);
        s += __shfl_down(s, 10);
        s += __shfl_down(s, 5);
        v[j] = s;
    }
    if (l < 5) {
        float wv[8];
        #pragma unroll
        for (int j = 0; j < 8; ++j) wv[j] = 0.125f * v[j] + b2[l * 8 + j];
        float m8 = wv[0];
        #pragma unroll
        for (int j = 1; j < 8; ++j) m8 = fmaxf(m8, wv[j]);
        float mx = m8;
        #pragma unroll
        for (int k = 0; k < 5; ++k) mx = fmaxf(mx, __shfl(m8, k));
        float se8 = 0.f;
        #pragma unroll
        for (int j = 0; j < 8; ++j) se8 += __expf(wv[j] - mx);
        float se = 0.f;
        #pragma unroll
        for (int k = 0; k < 5; ++k) se += __shfl(se8, k);
        float lse = mx + __logf(se);
        float* op = out + (size_t)node * 40 + l * 8;
        float4 o0 = {wv[0] - lse, wv[1] - lse, wv[2] - lse, wv[3] - lse};
        float4 o1 = {wv[4] - lse, wv[5] - lse, wv[6] - lse, wv[7] - lse};
        *(float4*)op = o0;
        *(float4*)(op + 4) = o1;
    }
}

// ---------------- launch ----------------

extern "C" void kernel_launch(void* const* d_in, const int* in_sizes, int n_in,
                              void* d_out, int out_size, void* d_ws, size_t ws_size,
                              hipStream_t stream) {
    const float* x      = (const float*)d_in[0];
    const int*   ei     = (const int*)d_in[1];
    const float* W1     = (const float*)d_in[2];
    const float* a_src1 = (const float*)d_in[3];
    const float* a_dst1 = (const float*)d_in[4];
    const float* b1     = (const float*)d_in[5];
    const float* W2     = (const float*)d_in[6];
    const float* a_src2 = (const float*)d_in[7];
    const float* a_dst2 = (const float*)d_in[8];
    const float* b2     = (const float*)d_in[9];
    float* out = (float*)d_out;

    const int n    = in_sizes[0] / 128;   // 50000
    const int E    = in_sizes[1] / 2;     // 800000
    const int Etot = E + n;
    const int EpM  = Etot + 7 * n + 16;   // upper bound on padded edge count
    const int nb   = (n + 255) / 256;     // scan blocks

    char* w = (char*)d_ws;
    auto take = [&](size_t bytes) {
        char* p = w;
        w += (bytes + 255) & ~(size_t)255;
        return p;
    };
    int*      deg    = (int*)take((size_t)n * 4);
    int*      rowptr = (int*)take((size_t)(n + 1) * 4);
    int*      cursor = (int*)take((size_t)n * 4);
    int*      bsum   = (int*)take((size_t)(nb + 1) * 4);
    int*      ssrc   = (int*)take((size_t)EpM * 4);
    ushort_t* xb     = (ushort_t*)take((size_t)n * 128 * 2);
    ushort_t* w1b    = (ushort_t*)take((size_t)272 * 128 * 2);   // 256 W1 rows + 16 wa rows
    ushort_t* w2b    = (ushort_t*)take((size_t)336 * 256 * 2);   // 320 W2 rows + 16 wa rows
    uchar_t*  h1f8   = (uchar_t*)take((size_t)(n + 1) * 256);
    ushort_t* helu   = (ushort_t*)take((size_t)n * 256 * 2);
    uchar_t*  h2f8   = (uchar_t*)take((size_t)(n + 1) * 320);
    float*    als1   = (float*)take((size_t)(n + 1) * 8 * 4);
    float*    ald1   = (float*)take((size_t)n * 8 * 4);
    float*    als2   = (float*)take((size_t)(n + 1) * 8 * 4);
    float*    ald2   = (float*)take((size_t)n * 8 * 4);

    hipMemsetAsync(deg, 0, (size_t)n * 4, stream);

    // merged prologue (W converts + wa folds + sentinel pads)
    prep_kernel<<<65, 256, 0, stream>>>(W1, W2, a_src1, a_dst1, a_src2, a_dst2,
                                        w1b, w2b, als1, als2, h1f8, h2f8, n);

    // merged x-convert + degree count, then CSR (3-phase parallel scan)
    int eb = (Etot + 255) / 256;
    convx_count_kernel<<<2048 + eb, 256, 0, stream>>>(x, xb, n * 128 / 4, ei, E, n, deg);
    scan_part_kernel<<<nb, 256, 0, stream>>>(deg, bsum, n);
    scan_top_kernel<<<1, 256, 0, stream>>>(bsum, nb);
    scan_write_kernel<<<nb, 256, 0, stream>>>(deg, bsum, rowptr, cursor, n);
    scatter_kernel<<<eb, 256, 0, stream>>>(ei, E, n, cursor, ssrc);
    pad_fill_kernel<<<(n + 255) / 256, 256, 0, stream>>>(rowptr, cursor, ssrc, n);

    int gb = (n + 127) / 128;
    int nb4 = (n + 3) / 4;

    // layer 1 (gemm computes fp8 h1 AND f32 als1/ald1)
    gemm_lds_al<17, 128><<<gb, 512, 0, stream>>>(xb, w1b, h1f8, als1, ald1, n);
    agg1_kernel<<<nb4, 256, 0, stream>>>(h1f8, als1, ald1, b1, rowptr, ssrc, helu, n);

    // layer 2
    gemm_lds_al<21, 256><<<gb, 512, 0, stream>>>(helu, w2b, h2f8, als2, ald2, n);
    agg2_kernel<<<nb4, 256, 0, stream>>>(h2f8, als2, ald2, b2, rowptr, ssrc, out, n);
}

// Round 17
// 257.101 us; speedup vs baseline: 1.5908x; 1.0042x over previous
//
#include <hip/hip_runtime.h>
#include <hip/hip_bf16.h>
#include <math.h>

typedef unsigned short ushort_t;
typedef unsigned char uchar_t;
typedef __attribute__((ext_vector_type(8))) short short8;
typedef __attribute__((ext_vector_type(4))) float f32x4;
typedef __attribute__((ext_vector_type(2))) float f32x2;
typedef __attribute__((ext_vector_type(4))) unsigned short u16x4;

#define LOG2E 1.44269504088896f

static __device__ __forceinline__ float b2f(ushort_t u) {
    union { unsigned int i; float f; } v; v.i = ((unsigned int)u) << 16; return v.f;
}
static __device__ __forceinline__ ushort_t f2b(float f) {
    unsigned int x = __float_as_uint(f);
    unsigned int r = (x + 0x7fffu + ((x >> 16) & 1u)) >> 16;
    return (ushort_t)r;
}
static __device__ __forceinline__ uchar_t f2e4m3(float f) {
    int r = __builtin_amdgcn_cvt_pk_fp8_f32(f, f, 0, false);
    return (uchar_t)(r & 0xff);
}
static __device__ __forceinline__ float exp2fast(float x) {
    return __builtin_amdgcn_exp2f(x);     // v_exp_f32 (2^x)
}

// ---------------- merged prologue: conv W1/W2, build wa1/wa2, pad rows ----------------

template<int K, int Cd>
static __device__ void wa_item(const float* __restrict__ W, const float* __restrict__ as,
                               const float* __restrict__ ad, ushort_t* __restrict__ Bext,
                               int rowoff, int tid) {
    int col = tid / K, k = tid - col * K;
    const float* a = (col < 8) ? as : ad;
    int h = col & 7;
    float s = 0.f;
    #pragma unroll 4
    for (int c = 0; c < Cd; ++c)
        s += W[(size_t)(h * Cd + c) * K + k] * a[h * Cd + c];
    Bext[(size_t)(rowoff + col) * K + k] = f2b(s * LOG2E);
}

__global__ void prep_kernel(const float* __restrict__ W1, const float* __restrict__ W2,
                            const float* __restrict__ as1, const float* __restrict__ ad1,
                            const float* __restrict__ as2, const float* __restrict__ ad2,
                            ushort_t* __restrict__ w1b, ushort_t* __restrict__ w2b,
                            float* als1, float* als2, uchar_t* h1f8, uchar_t* h2f8, int n) {
    int b = blockIdx.x, t = threadIdx.x;
    if (b < 40) {                     // conv W1 (8192 f4) + W2 (20480 f4)
        for (int i = b * 256 + t; i < 8192 + 20480; i += 40 * 256) {
            if (i < 8192) {
                float4 v = *(const float4*)(W1 + i * 4);
                u16x4 o = { f2b(v.x), f2b(v.y), f2b(v.z), f2b(v.w) };
                *(u16x4*)(w1b + i * 4) = o;
            } else {
                int j = i - 8192;
                float4 v = *(const float4*)(W2 + j * 4);
                u16x4 o = { f2b(v.x), f2b(v.y), f2b(v.z), f2b(v.w) };
                *(u16x4*)(w2b + j * 4) = o;
            }
        }
    } else if (b < 64) {              // wa1 (2048 items) + wa2 (4096 items)
        for (int i = (b - 40) * 256 + t; i < 2048 + 4096; i += 24 * 256) {
            if (i < 2048) wa_item<128, 32>(W1, as1, ad1, w1b, 256, i);
            else          wa_item<256, 40>(W2, as2, ad2, w2b, 320, i - 2048);
        }
    } else {                          // pads (sentinel row n)
        if (t < 8) { als1[(size_t)n * 8 + t] = -1e30f; als2[(size_t)n * 8 + t] = -1e30f; }
        h1f8[(size_t)n * 256 + t] = 0;
        h2f8[(size_t)n * 320 + t] = 0;
        if (t < 64) h2f8[(size_t)n * 320 + 256 + t] = 0;
    }
}

// ---------------- merged conv_x + degree count ----------------

__global__ void convx_count_kernel(const float* __restrict__ x, ushort_t* __restrict__ xb, int n4x,
                                   const int* __restrict__ ei, int E, int n, int* __restrict__ deg) {
    int b = blockIdx.x, t = threadIdx.x;
    if (b < 2048) {
        for (int i = b * 256 + t; i < n4x; i += 2048 * 256) {
            float4 v = *(const float4*)(x + i * 4);
            u16x4 o = { f2b(v.x), f2b(v.y), f2b(v.z), f2b(v.w) };
            *(u16x4*)(xb + i * 4) = o;
        }
    } else {
        int e = (b - 2048) * 256 + t;
        int Etot = E + n;
        if (e < Etot) {
            int dst = (e < E) ? ei[E + e] : (e - E);
            atomicAdd(&deg[dst], 1);
        }
    }
}

// ---------------- CSR build: 3-phase parallel scan (rows padded to multiples of 8) ----------------

__global__ void scan_part_kernel(const int* __restrict__ deg, int* __restrict__ bsum, int n) {
    int i = blockIdx.x * 256 + threadIdx.x;
    int v = (i < n) ? ((deg[i] + 7) & ~7) : 0;
    #pragma unroll
    for (int off = 1; off < 64; off <<= 1) v += __shfl_xor(v, off);
    __shared__ int ws[4];
    int wid = threadIdx.x >> 6, lane = threadIdx.x & 63;
    if (lane == 0) ws[wid] = v;
    __syncthreads();
    if (threadIdx.x == 0) bsum[blockIdx.x] = ws[0] + ws[1] + ws[2] + ws[3];
}

__global__ void scan_top_kernel(int* __restrict__ bsum, int nb) {
    int t = threadIdx.x;
    int v = (t < nb) ? bsum[t] : 0;
    int val = v;
    int lane = t & 63, wid = t >> 6;
    #pragma unroll
    for (int off = 1; off < 64; off <<= 1) {
        int nv = __shfl_up(val, off);
        if (lane >= off) val += nv;
    }
    __shared__ int ws[4];
    if (lane == 63) ws[wid] = val;
    __syncthreads();
    int pre = 0;
    for (int w = 0; w < 4; ++w) if (w < wid) pre += ws[w];
    if (t < nb) bsum[t] = pre + val - v;
}

__global__ void scan_write_kernel(const int* __restrict__ deg, const int* __restrict__ bsum,
                                  int* __restrict__ rowptr, int* __restrict__ cursor, int n) {
    int i = blockIdx.x * 256 + threadIdx.x;
    int t = threadIdx.x;
    int v = (i < n) ? ((deg[i] + 7) & ~7) : 0;
    int val = v;
    int lane = t & 63, wid = t >> 6;
    #pragma unroll
    for (int off = 1; off < 64; off <<= 1) {
        int nv = __shfl_up(val, off);
        if (lane >= off) val += nv;
    }
    __shared__ int ws[4];
    if (lane == 63) ws[wid] = val;
    __syncthreads();
    int pre = bsum[blockIdx.x];
    for (int w = 0; w < 4; ++w) if (w < wid) pre += ws[w];
    int excl = pre + val - v;
    if (i < n) { rowptr[i] = excl; cursor[i] = excl; }
    if (i == n - 1) rowptr[n] = excl + v;
}

__global__ void scatter_kernel(const int* __restrict__ ei, int E, int n,
                               int* __restrict__ cursor, int* __restrict__ ssrc) {
    int e = blockIdx.x * blockDim.x + threadIdx.x;
    int Etot = E + n;
    if (e >= Etot) return;
    int src, dst;
    if (e < E) { src = ei[e]; dst = ei[E + e]; }
    else       { src = e - E; dst = e - E; }
    int pos = atomicAdd(&cursor[dst], 1);
    ssrc[pos] = src;
}

__global__ void pad_fill_kernel(const int* __restrict__ rowptr, const int* __restrict__ cursor,
                                int* __restrict__ ssrc, int n) {
    int i = blockIdx.x * blockDim.x + threadIdx.x;
    if (i >= n) return;
    int p = cursor[i], e = rowptr[i + 1];
    for (; p < e; ++p) ssrc[p] = n;   // sentinel
}

// ---------------- bf16 MFMA NT GEMM + fused attention logits, fp8 feature output ----------------
// BM = 128 (8 waves x 16 rows), single accumulator set (known-good config).

template<int NFRAG, int K>
__global__ __launch_bounds__(512) void gemm_lds_al(const ushort_t* __restrict__ A,
                                                   const ushort_t* __restrict__ B,
                                                   uchar_t* __restrict__ C,
                                                   float* __restrict__ als,
                                                   float* __restrict__ ald, int M) {
    constexpr int N = NFRAG * 16;
    constexpr int NOUT = (NFRAG - 1) * 16;
    constexpr int RS = 40;                 // LDS row stride in elems
    constexpr int NK = K / 32;
    __shared__ ushort_t Bs[2][N * RS];
    const int t = threadIdx.x;
    const int w = t >> 6, l = t & 63;
    const int r0 = blockIdx.x * 128 + w * 16;
    int arow = r0 + (l & 15);
    if (arow >= M) arow = M - 1;
    const int koff = (l >> 4) * 8;
    const ushort_t* ap = A + (size_t)arow * K + koff;

    f32x4 acc[NFRAG];
    #pragma unroll
    for (int i = 0; i < NFRAG; ++i) acc[i] = (f32x4){0.f, 0.f, 0.f, 0.f};

    auto stage = [&](int buf, int k0) {
        #pragma unroll
        for (int c = t; c < N * 4; c += 512) {
            int row = c >> 2, part = (c & 3) << 3;           // part in elems
            *(short8*)&Bs[buf][row * RS + part] =
                *(const short8*)(B + (size_t)row * K + k0 + part);
        }
    };

    stage(0, 0);
    __syncthreads();
    #pragma unroll
    for (int kk = 0; kk < NK; ++kk) {
        int buf = kk & 1;
        if (kk + 1 < NK) stage(buf ^ 1, (kk + 1) * 32);
        short8 a = *(const short8*)(ap + kk * 32);
        #pragma unroll
        for (int nf = 0; nf < NFRAG; ++nf) {
            short8 b = *(const short8*)&Bs[buf][(nf * 16 + (l & 15)) * RS + koff];
            acc[nf] = __builtin_amdgcn_mfma_f32_16x16x32_bf16(a, b, acc[nf], 0, 0, 0);
        }
        __syncthreads();
    }

    const int crow0 = r0 + (l >> 4) * 4;
    #pragma unroll
    for (int nf = 0; nf < NFRAG - 1; ++nf) {
        #pragma unroll
        for (int j = 0; j < 4; ++j) {
            int row = crow0 + j;
            if (row < M) C[(size_t)row * NOUT + nf * 16 + (l & 15)] = f2e4m3(acc[nf][j]);
        }
    }
    {   // attention-logit fragment (pre-scaled by log2e)
        int col = l & 15;
        float* dstp = (col < 8) ? als : ald;
        int h = col & 7;
        #pragma unroll
        for (int j = 0; j < 4; ++j) {
            int row = crow0 + j;
            if (row < M) dstp[(size_t)row * 8 + h] = acc[NFRAG - 1][j];
        }
    }
}

// ---------------- layer-1 aggregation: 2-stage pipelined, no-max exp2 softmax, fp8 gather ----------------

__device__ __forceinline__ float lrelu(float e) { return (e > 0.f) ? e : 0.2f * e; }

__global__ void agg1_kernel(const uchar_t* __restrict__ h1, const float* __restrict__ als,
                            const float* __restrict__ aldv, const float* __restrict__ b1,
                            const int* __restrict__ rowptr, const int* __restrict__ ssrc,
                            ushort_t* __restrict__ hout, int n) {
    int node = blockIdx.x * 4 + (threadIdx.x >> 6);
    if (node >= n) return;
    int l = threadIdx.x & 63;
    int h = l >> 3;
    float ald = aldv[node * 8 + h];
    int beg = rowptr[node], end = rowptr[node + 1];
    float den = 0.f;
    f32x2 acc01 = {0.f, 0.f}, acc23 = {0.f, 0.f};

    // prologue: stage-0 loads (deg >= 1 always -> beg < end)
    int4 sA = *(const int4*)(ssrc + beg);
    int4 sB = *(const int4*)(ssrc + beg + 4);
    float e0 = als[sA.x * 8 + h], e1 = als[sA.y * 8 + h];
    float e2 = als[sA.z * 8 + h], e3 = als[sA.w * 8 + h];
    float e4 = als[sB.x * 8 + h], e5 = als[sB.y * 8 + h];
    float e6 = als[sB.z * 8 + h], e7 = als[sB.w * 8 + h];
    int g0 = *(const int*)(h1 + (size_t)sA.x * 256 + l * 4);
    int g1 = *(const int*)(h1 + (size_t)sA.y * 256 + l * 4);
    int g2 = *(const int*)(h1 + (size_t)sA.z * 256 + l * 4);
    int g3 = *(const int*)(h1 + (size_t)sA.w * 256 + l * 4);
    int g4 = *(const int*)(h1 + (size_t)sB.x * 256 + l * 4);
    int g5 = *(const int*)(h1 + (size_t)sB.y * 256 + l * 4);
    int g6 = *(const int*)(h1 + (size_t)sB.z * 256 + l * 4);
    int g7 = *(const int*)(h1 + (size_t)sB.w * 256 + l * 4);

    for (int p = beg; p < end; p += 8) {
        // issue stage-1 loads (last iter: reload current block, discarded)
        int pp = (p + 8 < end) ? (p + 8) : p;
        int4 tA = *(const int4*)(ssrc + pp);
        int4 tB = *(const int4*)(ssrc + pp + 4);
        float f0 = als[tA.x * 8 + h], f1 = als[tA.y * 8 + h];
        float f2 = als[tA.z * 8 + h], f3 = als[tA.w * 8 + h];
        float f4 = als[tB.x * 8 + h], f5 = als[tB.y * 8 + h];
        float f6 = als[tB.z * 8 + h], f7 = als[tB.w * 8 + h];
        int k0 = *(const int*)(h1 + (size_t)tA.x * 256 + l * 4);
        int k1 = *(const int*)(h1 + (size_t)tA.y * 256 + l * 4);
        int k2 = *(const int*)(h1 + (size_t)tA.z * 256 + l * 4);
        int k3 = *(const int*)(h1 + (size_t)tA.w * 256 + l * 4);
        int k4 = *(const int*)(h1 + (size_t)tB.x * 256 + l * 4);
        int k5 = *(const int*)(h1 + (size_t)tB.y * 256 + l * 4);
        int k6 = *(const int*)(h1 + (size_t)tB.z * 256 + l * 4);
        int k7 = *(const int*)(h1 + (size_t)tB.w * 256 + l * 4);
        // consume stage-0
        float w0 = exp2fast(lrelu(e0 + ald)), w1 = exp2fast(lrelu(e1 + ald));
        float w2 = exp2fast(lrelu(e2 + ald)), w3 = exp2fast(lrelu(e3 + ald));
        float w4 = exp2fast(lrelu(e4 + ald)), w5 = exp2fast(lrelu(e5 + ald));
        float w6 = exp2fast(lrelu(e6 + ald)), w7 = exp2fast(lrelu(e7 + ald));
        den += ((w0 + w1) + (w2 + w3)) + ((w4 + w5) + (w6 + w7));
        #define DQ(g, wv) { \
            f32x2 lo = __builtin_amdgcn_cvt_pk_f32_fp8(g, false); \
            f32x2 hi = __builtin_amdgcn_cvt_pk_f32_fp8(g, true);  \
            f32x2 w2v = {wv, wv}; \
            acc01 += w2v * lo; acc23 += w2v * hi; }
        DQ(g0, w0) DQ(g1, w1) DQ(g2, w2) DQ(g3, w3)
        DQ(g4, w4) DQ(g5, w5) DQ(g6, w6) DQ(g7, w7)
        #undef DQ
        // rotate
        e0 = f0; e1 = f1; e2 = f2; e3 = f3; e4 = f4; e5 = f5; e6 = f6; e7 = f7;
        g0 = k0; g1 = k1; g2 = k2; g3 = k3; g4 = k4; g5 = k5; g6 = k6; g7 = k7;
    }
    float inv = 1.f / den;
    float4 bv = *(const float4*)(b1 + l * 4);
    float v0 = acc01.x * inv + bv.x, v1 = acc01.y * inv + bv.y;
    float v2 = acc23.x * inv + bv.z, v3 = acc23.y * inv + bv.w;
    u16x4 o;
    o.x = f2b((v0 > 0.f) ? v0 : __expf(v0) - 1.f);
    o.y = f2b((v1 > 0.f) ? v1 : __expf(v1) - 1.f);
    o.z = f2b((v2 > 0.f) ? v2 : __expf(v2) - 1.f);
    o.w = f2b((v3 > 0.f) ? v3 : __expf(v3) - 1.f);
    *(u16x4*)(hout + (size_t)node * 256 + l * 4) = o;
}

// ---------------- layer-2 aggregation: 2-stage pipelined fp8 gather + head-mean + log_softmax ----------------

__global__ void agg2_kernel(const uchar_t* __restrict__ h2, const float* __restrict__ als,
                            const float* __restrict__ aldv, const float* __restrict__ b2,
                            const int* __restrict__ rowptr, const int* __restrict__ ssrc,
                            float* __restrict__ out, int n) {
    int node = blockIdx.x * 4 + (threadIdx.x >> 6);
    if (node >= n) return;
    int l = threadIdx.x & 63;
    int li = (l < 40) ? l : 0;
    int hd = li / 5;
    int cg = li - hd * 5;
    float ald = aldv[node * 8 + hd];
    int beg = rowptr[node], end = rowptr[node + 1];
    const uchar_t* base = h2 + hd * 40 + cg * 8;
    float den = 0.f;
    f32x2 acc01 = {0.f, 0.f}, acc23 = {0.f, 0.f}, acc45 = {0.f, 0.f}, acc67 = {0.f, 0.f};

    int4 sA = *(const int4*)(ssrc + beg);
    int4 sB = *(const int4*)(ssrc + beg + 4);
    float e0 = als[sA.x * 8 + hd], e1 = als[sA.y * 8 + hd];
    float e2 = als[sA.z * 8 + hd], e3 = als[sA.w * 8 + hd];
    float e4 = als[sB.x * 8 + hd], e5 = als[sB.y * 8 + hd];
    float e6 = als[sB.z * 8 + hd], e7 = als[sB.w * 8 + hd];
    uint2 g0 = *(const uint2*)(base + (size_t)sA.x * 320);
    uint2 g1 = *(const uint2*)(base + (size_t)sA.y * 320);
    uint2 g2 = *(const uint2*)(base + (size_t)sA.z * 320);
    uint2 g3 = *(const uint2*)(base + (size_t)sA.w * 320);
    uint2 g4 = *(const uint2*)(base + (size_t)sB.x * 320);
    uint2 g5 = *(const uint2*)(base + (size_t)sB.y * 320);
    uint2 g6 = *(const uint2*)(base + (size_t)sB.z * 320);
    uint2 g7 = *(const uint2*)(base + (size_t)sB.w * 320);

    for (int p = beg; p < end; p += 8) {
        int pp = (p + 8 < end) ? (p + 8) : p;
        int4 tA = *(const int4*)(ssrc + pp);
        int4 tB = *(const int4*)(ssrc + pp + 4);
        float f0 = als[tA.x * 8 + hd], f1 = als[tA.y * 8 + hd];
        float f2 = als[tA.z * 8 + hd], f3 = als[tA.w * 8 + hd];
        float f4 = als[tB.x * 8 + hd], f5 = als[tB.y * 8 + hd];
        float f6 = als[tB.z * 8 + hd], f7 = als[tB.w * 8 + hd];
        uint2 k0 = *(const uint2*)(base + (size_t)tA.x * 320);
        uint2 k1 = *(const uint2*)(base + (size_t)tA.y * 320);
        uint2 k2 = *(const uint2*)(base + (size_t)tA.z * 320);
        uint2 k3 = *(const uint2*)(base + (size_t)tA.w * 320);
        uint2 k4 = *(const uint2*)(base + (size_t)tB.x * 320);
        uint2 k5 = *(const uint2*)(base + (size_t)tB.y * 320);
        uint2 k6 = *(const uint2*)(base + (size_t)tB.z * 320);
        uint2 k7 = *(const uint2*)(base + (size_t)tB.w * 320);
        // consume stage-0
        float w0 = exp2fast(lrelu(e0 + ald)), w1 = exp2fast(lrelu(e1 + ald));
        float w2 = exp2fast(lrelu(e2 + ald)), w3 = exp2fast(lrelu(e3 + ald));
        float w4 = exp2fast(lrelu(e4 + ald)), w5 = exp2fast(lrelu(e5 + ald));
        float w6 = exp2fast(lrelu(e6 + ald)), w7 = exp2fast(lrelu(e7 + ald));
        den += ((w0 + w1) + (w2 + w3)) + ((w4 + w5) + (w6 + w7));
        #define DQ(g, wv) { \
            f32x2 q0 = __builtin_amdgcn_cvt_pk_f32_fp8((int)g.x, false); \
            f32x2 q1 = __builtin_amdgcn_cvt_pk_f32_fp8((int)g.x, true);  \
            f32x2 q2 = __builtin_amdgcn_cvt_pk_f32_fp8((int)g.y, false); \
            f32x2 q3 = __builtin_amdgcn_cvt_pk_f32_fp8((int)g.y, true);  \
            f32x2 w2v = {wv, wv}; \
            acc01 += w2v * q0; acc23 += w2v * q1; \
            acc45 += w2v * q2; acc67 += w2v * q3; }
        DQ(g0, w0) DQ(g1, w1) DQ(g2, w2) DQ(g3, w3)
        DQ(g4, w4) DQ(g5, w5) DQ(g6, w6) DQ(g7, w7)
        #undef DQ
        // rotate
        e0 = f0; e1 = f1; e2 = f2; e3 = f3; e4 = f4; e5 = f5; e6 = f6; e7 = f7;
        g0 = k0; g1 = k1; g2 = k2; g3 = k3; g4 = k4; g5 = k5; g6 = k6; g7 = k7;
    }
    float inv = 1.f / den;
    float v[8] = {acc01.x * inv, acc01.y * inv, acc23.x * inv, acc23.y * inv,
                  acc45.x * inv, acc45.y * inv, acc67.x * inv, acc67.y * inv};
    #pragma unroll
    for (int j = 0; j < 8; ++j) {
        float s = v[j];
        s += __shfl_down(s, 20);
        s += __shfl_down(s, 10);
        s += __shfl_down(s, 5);
        v[j] = s;
    }
    if (l < 5) {
        float wv[8];
        #pragma unroll
        for (int j = 0; j < 8; ++j) wv[j] = 0.125f * v[j] + b2[l * 8 + j];
        float m8 = wv[0];
        #pragma unroll
        for (int j = 1; j < 8; ++j) m8 = fmaxf(m8, wv[j]);
        float mx = m8;
        #pragma unroll
        for (int k = 0; k < 5; ++k) mx = fmaxf(mx, __shfl(m8, k));
        float se8 = 0.f;
        #pragma unroll
        for (int j = 0; j < 8; ++j) se8 += __expf(wv[j] - mx);
        float se = 0.f;
        #pragma unroll
        for (int k = 0; k < 5; ++k) se += __shfl(se8, k);
        float lse = mx + __logf(se);
        float* op = out + (size_t)node * 40 + l * 8;
        float4 o0 = {wv[0] - lse, wv[1] - lse, wv[2] - lse, wv[3] - lse};
        float4 o1 = {wv[4] - lse, wv[5] - lse, wv[6] - lse, wv[7] - lse};
        *(float4*)op = o0;
        *(float4*)(op + 4) = o1;
    }
}

// ---------------- launch ----------------

extern "C" void kernel_launch(void* const* d_in, const int* in_sizes, int n_in,
                              void* d_out, int out_size, void* d_ws, size_t ws_size,
                              hipStream_t stream) {
    const float* x      = (const float*)d_in[0];
    const int*   ei     = (const int*)d_in[1];
    const float* W1     = (const float*)d_in[2];
    const float* a_src1 = (const float*)d_in[3];
    const float* a_dst1 = (const float*)d_in[4];
    const float* b1     = (const float*)d_in[5];
    const float* W2     = (const float*)d_in[6];
    const float* a_src2 = (const float*)d_in[7];
    const float* a_dst2 = (const float*)d_in[8];
    const float* b2     = (const float*)d_in[9];
    float* out = (float*)d_out;

    const int n    = in_sizes[0] / 128;   // 50000
    const int E    = in_sizes[1] / 2;     // 800000
    const int Etot = E + n;
    const int EpM  = Etot + 7 * n + 16;   // upper bound on padded edge count
    const int nb   = (n + 255) / 256;     // scan blocks

    char* w = (char*)d_ws;
    auto take = [&](size_t bytes) {
        char* p = w;
        w += (bytes + 255) & ~(size_t)255;
        return p;
    };
    int*      deg    = (int*)take((size_t)n * 4);
    int*      rowptr = (int*)take((size_t)(n + 1) * 4);
    int*      cursor = (int*)take((size_t)n * 4);
    int*      bsum   = (int*)take((size_t)(nb + 1) * 4);
    int*      ssrc   = (int*)take((size_t)EpM * 4);
    ushort_t* xb     = (ushort_t*)take((size_t)n * 128 * 2);
    ushort_t* w1b    = (ushort_t*)take((size_t)272 * 128 * 2);   // 256 W1 rows + 16 wa rows
    ushort_t* w2b    = (ushort_t*)take((size_t)336 * 256 * 2);   // 320 W2 rows + 16 wa rows
    uchar_t*  h1f8   = (uchar_t*)take((size_t)(n + 1) * 256);
    ushort_t* helu   = (ushort_t*)take((size_t)n * 256 * 2);
    uchar_t*  h2f8   = (uchar_t*)take((size_t)(n + 1) * 320);
    float*    als1   = (float*)take((size_t)(n + 1) * 8 * 4);
    float*    ald1   = (float*)take((size_t)n * 8 * 4);
    float*    als2   = (float*)take((size_t)(n + 1) * 8 * 4);
    float*    ald2   = (float*)take((size_t)n * 8 * 4);

    hipMemsetAsync(deg, 0, (size_t)n * 4, stream);

    // merged prologue (W converts + wa folds + sentinel pads)
    prep_kernel<<<65, 256, 0, stream>>>(W1, W2, a_src1, a_dst1, a_src2, a_dst2,
                                        w1b, w2b, als1, als2, h1f8, h2f8, n);

    // merged x-convert + degree count, then CSR (3-phase parallel scan)
    int eb = (Etot + 255) / 256;
    convx_count_kernel<<<2048 + eb, 256, 0, stream>>>(x, xb, n * 128 / 4, ei, E, n, deg);
    scan_part_kernel<<<nb, 256, 0, stream>>>(deg, bsum, n);
    scan_top_kernel<<<1, 256, 0, stream>>>(bsum, nb);
    scan_write_kernel<<<nb, 256, 0, stream>>>(deg, bsum, rowptr, cursor, n);
    scatter_kernel<<<eb, 256, 0, stream>>>(ei, E, n, cursor, ssrc);
    pad_fill_kernel<<<(n + 255) / 256, 256, 0, stream>>>(rowptr, cursor, ssrc, n);

    int gb = (n + 127) / 128;
    int nb4 = (n + 3) / 4;

    // layer 1 (gemm computes fp8 h1 AND f32 als1/ald1)
    gemm_lds_al<17, 128><<<gb, 512, 0, stream>>>(xb, w1b, h1f8, als1, ald1, n);
    agg1_kernel<<<nb4, 256, 0, stream>>>(h1f8, als1, ald1, b1, rowptr, ssrc, helu, n);

    // layer 2
    gemm_lds_al<21, 256><<<gb, 512, 0, stream>>>(helu, w2b, h2f8, als2, ald2, n);
    agg2_kernel<<<nb4, 256, 0, stream>>>(h2f8, als2, ald2, b2, rowptr, ssrc, out, n);
}

// Round 18
// 250.823 us; speedup vs baseline: 1.6306x; 1.0250x over previous
//
#include <hip/hip_runtime.h>
#include <hip/hip_bf16.h>
#include <math.h>

typedef unsigned short ushort_t;
typedef unsigned char uchar_t;
typedef __attribute__((ext_vector_type(8))) short short8;
typedef __attribute__((ext_vector_type(4))) float f32x4;
typedef __attribute__((ext_vector_type(2))) float f32x2;
typedef __attribute__((ext_vector_type(4))) unsigned short u16x4;

#define LOG2E 1.44269504088896f

static __device__ __forceinline__ float b2f(ushort_t u) {
    union { unsigned int i; float f; } v; v.i = ((unsigned int)u) << 16; return v.f;
}
static __device__ __forceinline__ ushort_t f2b(float f) {
    unsigned int x = __float_as_uint(f);
    unsigned int r = (x + 0x7fffu + ((x >> 16) & 1u)) >> 16;
    return (ushort_t)r;
}
static __device__ __forceinline__ uchar_t f2e4m3(float f) {
    int r = __builtin_amdgcn_cvt_pk_fp8_f32(f, f, 0, false);
    return (uchar_t)(r & 0xff);
}
static __device__ __forceinline__ float exp2fast(float x) {
    return __builtin_amdgcn_exp2f(x);     // v_exp_f32 (2^x)
}

// ---------------- merged prologue: conv W1/W2, build wa1/wa2, pad rows, zero deg ----------------

template<int K, int Cd>
static __device__ void wa_item(const float* __restrict__ W, const float* __restrict__ as,
                               const float* __restrict__ ad, ushort_t* __restrict__ Bext,
                               int rowoff, int tid) {
    int col = tid / K, k = tid - col * K;
    const float* a = (col < 8) ? as : ad;
    int h = col & 7;
    float s = 0.f;
    #pragma unroll 4
    for (int c = 0; c < Cd; ++c)
        s += W[(size_t)(h * Cd + c) * K + k] * a[h * Cd + c];
    Bext[(size_t)(rowoff + col) * K + k] = f2b(s * LOG2E);
}

__global__ void prep_kernel(const float* __restrict__ W1, const float* __restrict__ W2,
                            const float* __restrict__ as1, const float* __restrict__ ad1,
                            const float* __restrict__ as2, const float* __restrict__ ad2,
                            ushort_t* __restrict__ w1b, ushort_t* __restrict__ w2b,
                            float* als1, float* als2, uchar_t* h1f8, uchar_t* h2f8,
                            int* __restrict__ deg, int n) {
    int b = blockIdx.x, t = threadIdx.x;
    if (b < 40) {                     // conv W1 (8192 f4) + W2 (20480 f4)
        for (int i = b * 256 + t; i < 8192 + 20480; i += 40 * 256) {
            if (i < 8192) {
                float4 v = *(const float4*)(W1 + i * 4);
                u16x4 o = { f2b(v.x), f2b(v.y), f2b(v.z), f2b(v.w) };
                *(u16x4*)(w1b + i * 4) = o;
            } else {
                int j = i - 8192;
                float4 v = *(const float4*)(W2 + j * 4);
                u16x4 o = { f2b(v.x), f2b(v.y), f2b(v.z), f2b(v.w) };
                *(u16x4*)(w2b + j * 4) = o;
            }
        }
    } else if (b < 64) {              // wa1 (2048 items) + wa2 (4096 items)
        for (int i = (b - 40) * 256 + t; i < 2048 + 4096; i += 24 * 256) {
            if (i < 2048) wa_item<128, 32>(W1, as1, ad1, w1b, 256, i);
            else          wa_item<256, 40>(W2, as2, ad2, w2b, 320, i - 2048);
        }
    } else if (b == 64) {             // pads (sentinel row n)
        if (t < 8) { als1[(size_t)n * 8 + t] = -1e30f; als2[(size_t)n * 8 + t] = -1e30f; }
        h1f8[(size_t)n * 256 + t] = 0;
        h2f8[(size_t)n * 320 + t] = 0;
        if (t < 64) h2f8[(size_t)n * 320 + 256 + t] = 0;
    } else {                          // zero deg
        int i = (b - 65) * 256 + t;
        if (i < n) deg[i] = 0;
    }
}

// ---------------- merged conv_x + degree count ----------------

__global__ void convx_count_kernel(const float* __restrict__ x, ushort_t* __restrict__ xb, int n4x,
                                   const int* __restrict__ ei, int E, int n, int* __restrict__ deg) {
    int b = blockIdx.x, t = threadIdx.x;
    if (b < 2048) {
        for (int i = b * 256 + t; i < n4x; i += 2048 * 256) {
            float4 v = *(const float4*)(x + i * 4);
            u16x4 o = { f2b(v.x), f2b(v.y), f2b(v.z), f2b(v.w) };
            *(u16x4*)(xb + i * 4) = o;
        }
    } else {
        int e = (b - 2048) * 256 + t;
        int Etot = E + n;
        if (e < Etot) {
            int dst = (e < E) ? ei[E + e] : (e - E);
            atomicAdd(&deg[dst], 1);
        }
    }
}

// ---------------- CSR build: 3-phase parallel scan; scan_write also prefills sentinels ----------------

__global__ void scan_part_kernel(const int* __restrict__ deg, int* __restrict__ bsum, int n) {
    int i = blockIdx.x * 256 + threadIdx.x;
    int v = (i < n) ? ((deg[i] + 7) & ~7) : 0;
    #pragma unroll
    for (int off = 1; off < 64; off <<= 1) v += __shfl_xor(v, off);
    __shared__ int ws[4];
    int wid = threadIdx.x >> 6, lane = threadIdx.x & 63;
    if (lane == 0) ws[wid] = v;
    __syncthreads();
    if (threadIdx.x == 0) bsum[blockIdx.x] = ws[0] + ws[1] + ws[2] + ws[3];
}

__global__ void scan_top_kernel(int* __restrict__ bsum, int nb) {
    int t = threadIdx.x;
    int v = (t < nb) ? bsum[t] : 0;
    int val = v;
    int lane = t & 63, wid = t >> 6;
    #pragma unroll
    for (int off = 1; off < 64; off <<= 1) {
        int nv = __shfl_up(val, off);
        if (lane >= off) val += nv;
    }
    __shared__ int ws[4];
    if (lane == 63) ws[wid] = val;
    __syncthreads();
    int pre = 0;
    for (int w = 0; w < 4; ++w) if (w < wid) pre += ws[w];
    if (t < nb) bsum[t] = pre + val - v;
}

__global__ void scan_write_kernel(const int* __restrict__ deg, const int* __restrict__ bsum,
                                  int* __restrict__ rowptr, int* __restrict__ cursor,
                                  int* __restrict__ ssrc, int n) {
    int i = blockIdx.x * 256 + threadIdx.x;
    int t = threadIdx.x;
    int v = (i < n) ? ((deg[i] + 7) & ~7) : 0;
    int val = v;
    int lane = t & 63, wid = t >> 6;
    #pragma unroll
    for (int off = 1; off < 64; off <<= 1) {
        int nv = __shfl_up(val, off);
        if (lane >= off) val += nv;
    }
    __shared__ int ws[4];
    if (lane == 63) ws[wid] = val;
    __syncthreads();
    int pre = bsum[blockIdx.x];
    for (int w = 0; w < 4; ++w) if (w < wid) pre += ws[w];
    int excl = pre + val - v;
    if (i < n) {
        rowptr[i] = excl; cursor[i] = excl;
        for (int p = excl; p < excl + v; ++p) ssrc[p] = n;   // sentinel prefill; scatter overwrites
    }
    if (i == n - 1) rowptr[n] = excl + v;
}

__global__ void scatter_kernel(const int* __restrict__ ei, int E, int n,
                               int* __restrict__ cursor, int* __restrict__ ssrc) {
    int e = blockIdx.x * blockDim.x + threadIdx.x;
    int Etot = E + n;
    if (e >= Etot) return;
    int src, dst;
    if (e < E) { src = ei[e]; dst = ei[E + e]; }
    else       { src = e - E; dst = e - E; }
    int pos = atomicAdd(&cursor[dst], 1);
    ssrc[pos] = src;
}

// ---------------- bf16 MFMA NT GEMM + fused attention logits, fp8 feature output ----------------
// BM = 128 (8 waves x 16 rows), single accumulator set (known-good config).

template<int NFRAG, int K>
__global__ __launch_bounds__(512) void gemm_lds_al(const ushort_t* __restrict__ A,
                                                   const ushort_t* __restrict__ B,
                                                   uchar_t* __restrict__ C,
                                                   float* __restrict__ als,
                                                   float* __restrict__ ald, int M) {
    constexpr int N = NFRAG * 16;
    constexpr int NOUT = (NFRAG - 1) * 16;
    constexpr int RS = 40;                 // LDS row stride in elems
    constexpr int NK = K / 32;
    __shared__ ushort_t Bs[2][N * RS];
    const int t = threadIdx.x;
    const int w = t >> 6, l = t & 63;
    const int r0 = blockIdx.x * 128 + w * 16;
    int arow = r0 + (l & 15);
    if (arow >= M) arow = M - 1;
    const int koff = (l >> 4) * 8;
    const ushort_t* ap = A + (size_t)arow * K + koff;

    f32x4 acc[NFRAG];
    #pragma unroll
    for (int i = 0; i < NFRAG; ++i) acc[i] = (f32x4){0.f, 0.f, 0.f, 0.f};

    auto stage = [&](int buf, int k0) {
        #pragma unroll
        for (int c = t; c < N * 4; c += 512) {
            int row = c >> 2, part = (c & 3) << 3;           // part in elems
            *(short8*)&Bs[buf][row * RS + part] =
                *(const short8*)(B + (size_t)row * K + k0 + part);
        }
    };

    stage(0, 0);
    __syncthreads();
    #pragma unroll
    for (int kk = 0; kk < NK; ++kk) {
        int buf = kk & 1;
        if (kk + 1 < NK) stage(buf ^ 1, (kk + 1) * 32);
        short8 a = *(const short8*)(ap + kk * 32);
        #pragma unroll
        for (int nf = 0; nf < NFRAG; ++nf) {
            short8 b = *(const short8*)&Bs[buf][(nf * 16 + (l & 15)) * RS + koff];
            acc[nf] = __builtin_amdgcn_mfma_f32_16x16x32_bf16(a, b, acc[nf], 0, 0, 0);
        }
        __syncthreads();
    }

    const int crow0 = r0 + (l >> 4) * 4;
    #pragma unroll
    for (int nf = 0; nf < NFRAG - 1; ++nf) {
        #pragma unroll
        for (int j = 0; j < 4; ++j) {
            int row = crow0 + j;
            if (row < M) C[(size_t)row * NOUT + nf * 16 + (l & 15)] = f2e4m3(acc[nf][j]);
        }
    }
    {   // attention-logit fragment (pre-scaled by log2e)
        int col = l & 15;
        float* dstp = (col < 8) ? als : ald;
        int h = col & 7;
        #pragma unroll
        for (int j = 0; j < 4; ++j) {
            int row = crow0 + j;
            if (row < M) dstp[(size_t)row * 8 + h] = acc[NFRAG - 1][j];
        }
    }
}

// ---------------- layer-1 aggregation: half-wave split (2 edges/slot), fp8 gather ----------------
// lanes 0-31 take even 4-edge group, lanes 32-63 odd; each lane owns 8 features (8B of row).

__device__ __forceinline__ float lrelu(float e) { return (e > 0.f) ? e : 0.2f * e; }

__global__ void agg1_kernel(const uchar_t* __restrict__ h1, const float* __restrict__ als,
                            const float* __restrict__ aldv, const float* __restrict__ b1,
                            const int* __restrict__ rowptr, const int* __restrict__ ssrc,
                            ushort_t* __restrict__ hout, int n) {
    int node = blockIdx.x * 4 + (threadIdx.x >> 6);
    if (node >= n) return;
    int l = threadIdx.x & 63;
    int half = l >> 5, ll = l & 31;
    int hd = ll >> 2;                      // features 8*ll..8*ll+7 all in head ll>>2
    float ald = aldv[node * 8 + hd];
    int beg = rowptr[node], end = rowptr[node + 1];
    float den = 0.f;
    f32x2 a0 = {0.f, 0.f}, a1 = {0.f, 0.f}, a2 = {0.f, 0.f}, a3 = {0.f, 0.f};
    const uchar_t* fb = h1 + ll * 8;
    for (int p = beg; p < end; p += 8) {
        int4 s4 = *(const int4*)(ssrc + p + half * 4);
        float e0 = als[s4.x * 8 + hd], e1 = als[s4.y * 8 + hd];
        float e2 = als[s4.z * 8 + hd], e3 = als[s4.w * 8 + hd];
        uint2 g0 = *(const uint2*)(fb + (size_t)s4.x * 256);
        uint2 g1 = *(const uint2*)(fb + (size_t)s4.y * 256);
        uint2 g2 = *(const uint2*)(fb + (size_t)s4.z * 256);
        uint2 g3 = *(const uint2*)(fb + (size_t)s4.w * 256);
        float w0 = exp2fast(lrelu(e0 + ald)), w1 = exp2fast(lrelu(e1 + ald));
        float w2 = exp2fast(lrelu(e2 + ald)), w3 = exp2fast(lrelu(e3 + ald));
        den += (w0 + w1) + (w2 + w3);
        #define DQ(g, wv) { \
            f32x2 q0 = __builtin_amdgcn_cvt_pk_f32_fp8((int)g.x, false); \
            f32x2 q1 = __builtin_amdgcn_cvt_pk_f32_fp8((int)g.x, true);  \
            f32x2 q2 = __builtin_amdgcn_cvt_pk_f32_fp8((int)g.y, false); \
            f32x2 q3 = __builtin_amdgcn_cvt_pk_f32_fp8((int)g.y, true);  \
            f32x2 w2v = {wv, wv}; \
            a0 += w2v * q0; a1 += w2v * q1; a2 += w2v * q2; a3 += w2v * q3; }
        DQ(g0, w0) DQ(g1, w1) DQ(g2, w2) DQ(g3, w3)
        #undef DQ
    }
    // merge halves (lane ^ 32)
    den += __shfl_xor(den, 32);
    a0.x += __shfl_xor(a0.x, 32); a0.y += __shfl_xor(a0.y, 32);
    a1.x += __shfl_xor(a1.x, 32); a1.y += __shfl_xor(a1.y, 32);
    a2.x += __shfl_xor(a2.x, 32); a2.y += __shfl_xor(a2.y, 32);
    a3.x += __shfl_xor(a3.x, 32); a3.y += __shfl_xor(a3.y, 32);
    if (half == 0) {
        float inv = 1.f / den;
        float4 bv0 = *(const float4*)(b1 + ll * 8);
        float4 bv1 = *(const float4*)(b1 + ll * 8 + 4);
        float v0 = a0.x * inv + bv0.x, v1 = a0.y * inv + bv0.y;
        float v2 = a1.x * inv + bv0.z, v3 = a1.y * inv + bv0.w;
        float v4 = a2.x * inv + bv1.x, v5 = a2.y * inv + bv1.y;
        float v6 = a3.x * inv + bv1.z, v7 = a3.y * inv + bv1.w;
        u16x4 o0, o1;
        o0.x = f2b((v0 > 0.f) ? v0 : __expf(v0) - 1.f);
        o0.y = f2b((v1 > 0.f) ? v1 : __expf(v1) - 1.f);
        o0.z = f2b((v2 > 0.f) ? v2 : __expf(v2) - 1.f);
        o0.w = f2b((v3 > 0.f) ? v3 : __expf(v3) - 1.f);
        o1.x = f2b((v4 > 0.f) ? v4 : __expf(v4) - 1.f);
        o1.y = f2b((v5 > 0.f) ? v5 : __expf(v5) - 1.f);
        o1.z = f2b((v6 > 0.f) ? v6 : __expf(v6) - 1.f);
        o1.w = f2b((v7 > 0.f) ? v7 : __expf(v7) - 1.f);
        ushort_t* op = hout + (size_t)node * 256 + ll * 8;
        *(u16x4*)op = o0;
        *(u16x4*)(op + 4) = o1;
    }
}

// ---------------- layer-2 aggregation: 8-edge unrolled fp8 gather + head-mean + log_softmax ----------------

__global__ void agg2_kernel(const uchar_t* __restrict__ h2, const float* __restrict__ als,
                            const float* __restrict__ aldv, const float* __restrict__ b2,
                            const int* __restrict__ rowptr, const int* __restrict__ ssrc,
                            float* __restrict__ out, int n) {
    int node = blockIdx.x * 4 + (threadIdx.x >> 6);
    if (node >= n) return;
    int l = threadIdx.x & 63;
    int li = (l < 40) ? l : 0;
    int hd = li / 5;
    int cg = li - hd * 5;
    float ald = aldv[node * 8 + hd];
    int beg = rowptr[node], end = rowptr[node + 1];
    const uchar_t* base = h2 + hd * 40 + cg * 8;
    float den = 0.f;
    f32x2 acc01 = {0.f, 0.f}, acc23 = {0.f, 0.f}, acc45 = {0.f, 0.f}, acc67 = {0.f, 0.f};
    for (int p = beg; p < end; p += 8) {
        int4 sA = *(const int4*)(ssrc + p);
        int4 sB = *(const int4*)(ssrc + p + 4);
        float w0 = exp2fast(lrelu(als[sA.x * 8 + hd] + ald));
        float w1 = exp2fast(lrelu(als[sA.y * 8 + hd] + ald));
        float w2 = exp2fast(lrelu(als[sA.z * 8 + hd] + ald));
        float w3 = exp2fast(lrelu(als[sA.w * 8 + hd] + ald));
        float w4 = exp2fast(lrelu(als[sB.x * 8 + hd] + ald));
        float w5 = exp2fast(lrelu(als[sB.y * 8 + hd] + ald));
        float w6 = exp2fast(lrelu(als[sB.z * 8 + hd] + ald));
        float w7 = exp2fast(lrelu(als[sB.w * 8 + hd] + ald));
        uint2 g0 = *(const uint2*)(base + (size_t)sA.x * 320);
        uint2 g1 = *(const uint2*)(base + (size_t)sA.y * 320);
        uint2 g2 = *(const uint2*)(base + (size_t)sA.z * 320);
        uint2 g3 = *(const uint2*)(base + (size_t)sA.w * 320);
        uint2 g4 = *(const uint2*)(base + (size_t)sB.x * 320);
        uint2 g5 = *(const uint2*)(base + (size_t)sB.y * 320);
        uint2 g6 = *(const uint2*)(base + (size_t)sB.z * 320);
        uint2 g7 = *(const uint2*)(base + (size_t)sB.w * 320);
        den += ((w0 + w1) + (w2 + w3)) + ((w4 + w5) + (w6 + w7));
        #define DQ(g, wv) { \
            f32x2 q0 = __builtin_amdgcn_cvt_pk_f32_fp8((int)g.x, false); \
            f32x2 q1 = __builtin_amdgcn_cvt_pk_f32_fp8((int)g.x, true);  \
            f32x2 q2 = __builtin_amdgcn_cvt_pk_f32_fp8((int)g.y, false); \
            f32x2 q3 = __builtin_amdgcn_cvt_pk_f32_fp8((int)g.y, true);  \
            f32x2 w2v = {wv, wv}; \
            acc01 += w2v * q0; acc23 += w2v * q1; \
            acc45 += w2v * q2; acc67 += w2v * q3; }
        DQ(g0, w0) DQ(g1, w1) DQ(g2, w2) DQ(g3, w3)
        DQ(g4, w4) DQ(g5, w5) DQ(g6, w6) DQ(g7, w7)
        #undef DQ
    }
    float inv = 1.f / den;
    float v[8] = {acc01.x * inv, acc01.y * inv, acc23.x * inv, acc23.y * inv,
                  acc45.x * inv, acc45.y * inv, acc67.x * inv, acc67.y * inv};
    #pragma unroll
    for (int j = 0; j < 8; ++j) {
        float s = v[j];
        s += __shfl_down(s, 20);
        s += __shfl_down(s, 10);
        s += __shfl_down(s, 5);
        v[j] = s;
    }
    if (l < 5) {
        float wv[8];
        #pragma unroll
        for (int j = 0; j < 8; ++j) wv[j] = 0.125f * v[j] + b2[l * 8 + j];
        float m8 = wv[0];
        #pragma unroll
        for (int j = 1; j < 8; ++j) m8 = fmaxf(m8, wv[j]);
        float mx = m8;
        #pragma unroll
        for (int k = 0; k < 5; ++k) mx = fmaxf(mx, __shfl(m8, k));
        float se8 = 0.f;
        #pragma unroll
        for (int j = 0; j < 8; ++j) se8 += __expf(wv[j] - mx);
        float se = 0.f;
        #pragma unroll
        for (int k = 0; k < 5; ++k) se += __shfl(se8, k);
        float lse = mx + __logf(se);
        float* op = out + (size_t)node * 40 + l * 8;
        float4 o0 = {wv[0] - lse, wv[1] - lse, wv[2] - lse, wv[3] - lse};
        float4 o1 = {wv[4] - lse, wv[5] - lse, wv[6] - lse, wv[7] - lse};
        *(float4*)op = o0;
        *(float4*)(op + 4) = o1;
    }
}

// ---------------- launch ----------------

extern "C" void kernel_launch(void* const* d_in, const int* in_sizes, int n_in,
                              void* d_out, int out_size, void* d_ws, size_t ws_size,
                              hipStream_t stream) {
    const float* x      = (const float*)d_in[0];
    const int*   ei     = (const int*)d_in[1];
    const float* W1     = (const float*)d_in[2];
    const float* a_src1 = (const float*)d_in[3];
    const float* a_dst1 = (const float*)d_in[4];
    const float* b1     = (const float*)d_in[5];
    const float* W2     = (const float*)d_in[6];
    const float* a_src2 = (const float*)d_in[7];
    const float* a_dst2 = (const float*)d_in[8];
    const float* b2     = (const float*)d_in[9];
    float* out = (float*)d_out;

    const int n    = in_sizes[0] / 128;   // 50000
    const int E    = in_sizes[1] / 2;     // 800000
    const int Etot = E + n;
    const int EpM  = Etot + 7 * n + 16;   // upper bound on padded edge count
    const int nb   = (n + 255) / 256;     // scan blocks

    char* w = (char*)d_ws;
    auto take = [&](size_t bytes) {
        char* p = w;
        w += (bytes + 255) & ~(size_t)255;
        return p;
    };
    int*      deg    = (int*)take((size_t)n * 4);
    int*      rowptr = (int*)take((size_t)(n + 1) * 4);
    int*      cursor = (int*)take((size_t)n * 4);
    int*      bsum   = (int*)take((size_t)(nb + 1) * 4);
    int*      ssrc   = (int*)take((size_t)EpM * 4);
    ushort_t* xb     = (ushort_t*)take((size_t)n * 128 * 2);
    ushort_t* w1b    = (ushort_t*)take((size_t)272 * 128 * 2);   // 256 W1 rows + 16 wa rows
    ushort_t* w2b    = (ushort_t*)take((size_t)336 * 256 * 2);   // 320 W2 rows + 16 wa rows
    uchar_t*  h1f8   = (uchar_t*)take((size_t)(n + 1) * 256);
    ushort_t* helu   = (ushort_t*)take((size_t)n * 256 * 2);
    uchar_t*  h2f8   = (uchar_t*)take((size_t)(n + 1) * 320);
    float*    als1   = (float*)take((size_t)(n + 1) * 8 * 4);
    float*    ald1   = (float*)take((size_t)n * 8 * 4);
    float*    als2   = (float*)take((size_t)(n + 1) * 8 * 4);
    float*    ald2   = (float*)take((size_t)n * 8 * 4);

    // merged prologue (W converts + wa folds + sentinel pads + deg zero)
    prep_kernel<<<65 + nb, 256, 0, stream>>>(W1, W2, a_src1, a_dst1, a_src2, a_dst2,
                                             w1b, w2b, als1, als2, h1f8, h2f8, deg, n);

    // merged x-convert + degree count, then CSR (3-phase parallel scan, sentinel prefill)
    int eb = (Etot + 255) / 256;
    convx_count_kernel<<<2048 + eb, 256, 0, stream>>>(x, xb, n * 128 / 4, ei, E, n, deg);
    scan_part_kernel<<<nb, 256, 0, stream>>>(deg, bsum, n);
    scan_top_kernel<<<1, 256, 0, stream>>>(bsum, nb);
    scan_write_kernel<<<nb, 256, 0, stream>>>(deg, bsum, rowptr, cursor, ssrc, n);
    scatter_kernel<<<eb, 256, 0, stream>>>(ei, E, n, cursor, ssrc);

    int gb = (n + 127) / 128;
    int nb4 = (n + 3) / 4;

    // layer 1 (gemm computes fp8 h1 AND f32 als1/ald1)
    gemm_lds_al<17, 128><<<gb, 512, 0, stream>>>(xb, w1b, h1f8, als1, ald1, n);
    agg1_kernel<<<nb4, 256, 0, stream>>>(h1f8, als1, ald1, b1, rowptr, ssrc, helu, n);

    // layer 2
    gemm_lds_al<21, 256><<<gb, 512, 0, stream>>>(helu, w2b, h2f8, als2, ald2, n);
    agg2_kernel<<<nb4, 256, 0, stream>>>(h2f8, als2, ald2, b2, rowptr, ssrc, out, n);
}

// Round 21
// 247.890 us; speedup vs baseline: 1.6499x; 1.0118x over previous
//
#include <hip/hip_runtime.h>
#include <hip/hip_bf16.h>
#include <math.h>

typedef unsigned short ushort_t;
typedef unsigned char uchar_t;
typedef __attribute__((ext_vector_type(8))) short short8;
typedef __attribute__((ext_vector_type(4))) float f32x4;
typedef __attribute__((ext_vector_type(2))) float f32x2;
typedef __attribute__((ext_vector_type(4))) unsigned short u16x4;

#define LOG2E 1.44269504088896f

static __device__ __forceinline__ float b2f(ushort_t u) {
    union { unsigned int i; float f; } v; v.i = ((unsigned int)u) << 16; return v.f;
}
static __device__ __forceinline__ ushort_t f2b(float f) {
    unsigned int x = __float_as_uint(f);
    unsigned int r = (x + 0x7fffu + ((x >> 16) & 1u)) >> 16;
    return (ushort_t)r;
}
static __device__ __forceinline__ uchar_t f2e4m3(float f) {
    int r = __builtin_amdgcn_cvt_pk_fp8_f32(f, f, 0, false);
    return (uchar_t)(r & 0xff);
}
static __device__ __forceinline__ float exp2fast(float x) {
    return __builtin_amdgcn_exp2f(x);     // v_exp_f32 (2^x)
}

// ---------------- merged prologue: conv W1/W2, build wa1/wa2, pad rows, zero deg ----------------

template<int K, int Cd>
static __device__ void wa_item(const float* __restrict__ W, const float* __restrict__ as,
                               const float* __restrict__ ad, ushort_t* __restrict__ Bext,
                               int rowoff, int tid) {
    int col = tid / K, k = tid - col * K;
    const float* a = (col < 8) ? as : ad;
    int h = col & 7;
    float s = 0.f;
    #pragma unroll 4
    for (int c = 0; c < Cd; ++c)
        s += W[(size_t)(h * Cd + c) * K + k] * a[h * Cd + c];
    Bext[(size_t)(rowoff + col) * K + k] = f2b(s * LOG2E);
}

__global__ void prep_kernel(const float* __restrict__ W1, const float* __restrict__ W2,
                            const float* __restrict__ as1, const float* __restrict__ ad1,
                            const float* __restrict__ as2, const float* __restrict__ ad2,
                            ushort_t* __restrict__ w1b, ushort_t* __restrict__ w2b,
                            float* als1, float* als2, uchar_t* h1f8, uchar_t* h2f8,
                            int* __restrict__ deg, int n) {
    int b = blockIdx.x, t = threadIdx.x;
    if (b < 40) {                     // conv W1 (8192 f4) + W2 (20480 f4)
        for (int i = b * 256 + t; i < 8192 + 20480; i += 40 * 256) {
            if (i < 8192) {
                float4 v = *(const float4*)(W1 + i * 4);
                u16x4 o = { f2b(v.x), f2b(v.y), f2b(v.z), f2b(v.w) };
                *(u16x4*)(w1b + i * 4) = o;
            } else {
                int j = i - 8192;
                float4 v = *(const float4*)(W2 + j * 4);
                u16x4 o = { f2b(v.x), f2b(v.y), f2b(v.z), f2b(v.w) };
                *(u16x4*)(w2b + j * 4) = o;
            }
        }
    } else if (b < 64) {              // wa1 (2048 items) + wa2 (4096 items)
        for (int i = (b - 40) * 256 + t; i < 2048 + 4096; i += 24 * 256) {
            if (i < 2048) wa_item<128, 32>(W1, as1, ad1, w1b, 256, i);
            else          wa_item<256, 40>(W2, as2, ad2, w2b, 320, i - 2048);
        }
    } else if (b == 64) {             // pads (sentinel row n)
        if (t < 8) { als1[(size_t)n * 8 + t] = -1e30f; als2[(size_t)n * 8 + t] = -1e30f; }
        h1f8[(size_t)n * 256 + t] = 0;
        h2f8[(size_t)n * 320 + t] = 0;
        if (t < 64) h2f8[(size_t)n * 320 + 256 + t] = 0;
    } else {                          // zero deg
        int i = (b - 65) * 256 + t;
        if (i < n) deg[i] = 0;
    }
}

// ---------------- merged conv_x + degree count ----------------

__global__ void convx_count_kernel(const float* __restrict__ x, ushort_t* __restrict__ xb, int n4x,
                                   const int* __restrict__ ei, int E, int n, int* __restrict__ deg) {
    int b = blockIdx.x, t = threadIdx.x;
    if (b < 2048) {
        for (int i = b * 256 + t; i < n4x; i += 2048 * 256) {
            float4 v = *(const float4*)(x + i * 4);
            u16x4 o = { f2b(v.x), f2b(v.y), f2b(v.z), f2b(v.w) };
            *(u16x4*)(xb + i * 4) = o;
        }
    } else {
        int e = (b - 2048) * 256 + t;
        int Etot = E + n;
        if (e < Etot) {
            int dst = (e < E) ? ei[E + e] : (e - E);
            atomicAdd(&deg[dst], 1);
        }
    }
}

// ---------------- CSR build: 3-phase parallel scan; scan_write also prefills sentinels ----------------

__global__ void scan_part_kernel(const int* __restrict__ deg, int* __restrict__ bsum, int n) {
    int i = blockIdx.x * 256 + threadIdx.x;
    int v = (i < n) ? ((deg[i] + 7) & ~7) : 0;
    #pragma unroll
    for (int off = 1; off < 64; off <<= 1) v += __shfl_xor(v, off);
    __shared__ int ws[4];
    int wid = threadIdx.x >> 6, lane = threadIdx.x & 63;
    if (lane == 0) ws[wid] = v;
    __syncthreads();
    if (threadIdx.x == 0) bsum[blockIdx.x] = ws[0] + ws[1] + ws[2] + ws[3];
}

__global__ void scan_top_kernel(int* __restrict__ bsum, int nb) {
    int t = threadIdx.x;
    int v = (t < nb) ? bsum[t] : 0;
    int val = v;
    int lane = t & 63, wid = t >> 6;
    #pragma unroll
    for (int off = 1; off < 64; off <<= 1) {
        int nv = __shfl_up(val, off);
        if (lane >= off) val += nv;
    }
    __shared__ int ws[4];
    if (lane == 63) ws[wid] = val;
    __syncthreads();
    int pre = 0;
    for (int w = 0; w < 4; ++w) if (w < wid) pre += ws[w];
    if (t < nb) bsum[t] = pre + val - v;
}

__global__ void scan_write_kernel(const int* __restrict__ deg, const int* __restrict__ bsum,
                                  int* __restrict__ rowptr, int* __restrict__ cursor,
                                  int* __restrict__ ssrc, int n) {
    int i = blockIdx.x * 256 + threadIdx.x;
    int t = threadIdx.x;
    int v = (i < n) ? ((deg[i] + 7) & ~7) : 0;
    int val = v;
    int lane = t & 63, wid = t >> 6;
    #pragma unroll
    for (int off = 1; off < 64; off <<= 1) {
        int nv = __shfl_up(val, off);
        if (lane >= off) val += nv;
    }
    __shared__ int ws[4];
    if (lane == 63) ws[wid] = val;
    __syncthreads();
    int pre = bsum[blockIdx.x];
    for (int w = 0; w < 4; ++w) if (w < wid) pre += ws[w];
    int excl = pre + val - v;
    if (i < n) {
        rowptr[i] = excl; cursor[i] = excl;
        for (int p = excl; p < excl + v; ++p) ssrc[p] = n;   // sentinel prefill; scatter overwrites
    }
    if (i == n - 1) rowptr[n] = excl + v;
}

__global__ void scatter_kernel(const int* __restrict__ ei, int E, int n,
                               int* __restrict__ cursor, int* __restrict__ ssrc) {
    int e = blockIdx.x * blockDim.x + threadIdx.x;
    int Etot = E + n;
    if (e >= Etot) return;
    int src, dst;
    if (e < E) { src = ei[e]; dst = ei[E + e]; }
    else       { src = e - E; dst = e - E; }
    int pos = atomicAdd(&cursor[dst], 1);
    ssrc[pos] = src;
}

// ---------------- bf16 MFMA NT GEMM + fused attention logits, fp8 feature output ----------------
// BM = 128 (8 waves x 16 rows), single accumulator set (known-good config).

template<int NFRAG, int K>
__global__ __launch_bounds__(512) void gemm_lds_al(const ushort_t* __restrict__ A,
                                                   const ushort_t* __restrict__ B,
                                                   uchar_t* __restrict__ C,
                                                   float* __restrict__ als,
                                                   float* __restrict__ ald, int M) {
    constexpr int N = NFRAG * 16;
    constexpr int NOUT = (NFRAG - 1) * 16;
    constexpr int RS = 40;                 // LDS row stride in elems
    constexpr int NK = K / 32;
    __shared__ ushort_t Bs[2][N * RS];
    const int t = threadIdx.x;
    const int w = t >> 6, l = t & 63;
    const int r0 = blockIdx.x * 128 + w * 16;
    int arow = r0 + (l & 15);
    if (arow >= M) arow = M - 1;
    const int koff = (l >> 4) * 8;
    const ushort_t* ap = A + (size_t)arow * K + koff;

    f32x4 acc[NFRAG];
    #pragma unroll
    for (int i = 0; i < NFRAG; ++i) acc[i] = (f32x4){0.f, 0.f, 0.f, 0.f};

    auto stage = [&](int buf, int k0) {
        #pragma unroll
        for (int c = t; c < N * 4; c += 512) {
            int row = c >> 2, part = (c & 3) << 3;           // part in elems
            *(short8*)&Bs[buf][row * RS + part] =
                *(const short8*)(B + (size_t)row * K + k0 + part);
        }
    };

    stage(0, 0);
    __syncthreads();
    #pragma unroll
    for (int kk = 0; kk < NK; ++kk) {
        int buf = kk & 1;
        if (kk + 1 < NK) stage(buf ^ 1, (kk + 1) * 32);
        short8 a = *(const short8*)(ap + kk * 32);
        #pragma unroll
        for (int nf = 0; nf < NFRAG; ++nf) {
            short8 b = *(const short8*)&Bs[buf][(nf * 16 + (l & 15)) * RS + koff];
            acc[nf] = __builtin_amdgcn_mfma_f32_16x16x32_bf16(a, b, acc[nf], 0, 0, 0);
        }
        __syncthreads();
    }

    const int crow0 = r0 + (l >> 4) * 4;
    #pragma unroll
    for (int nf = 0; nf < NFRAG - 1; ++nf) {
        #pragma unroll
        for (int j = 0; j < 4; ++j) {
            int row = crow0 + j;
            if (row < M) C[(size_t)row * NOUT + nf * 16 + (l & 15)] = f2e4m3(acc[nf][j]);
        }
    }
    {   // attention-logit fragment (pre-scaled by log2e)
        int col = l & 15;
        float* dstp = (col < 8) ? als : ald;
        int h = col & 7;
        #pragma unroll
        for (int j = 0; j < 4; ++j) {
            int row = crow0 + j;
            if (row < M) dstp[(size_t)row * 8 + h] = acc[NFRAG - 1][j];
        }
    }
}

// ---------------- layer-1 aggregation: half-wave split (2 edges/slot), fp8 gather ----------------

__device__ __forceinline__ float lrelu(float e) { return (e > 0.f) ? e : 0.2f * e; }

__global__ void agg1_kernel(const uchar_t* __restrict__ h1, const float* __restrict__ als,
                            const float* __restrict__ aldv, const float* __restrict__ b1,
                            const int* __restrict__ rowptr, const int* __restrict__ ssrc,
                            ushort_t* __restrict__ hout, int n) {
    int node = blockIdx.x * 4 + (threadIdx.x >> 6);
    if (node >= n) return;
    int l = threadIdx.x & 63;
    int half = l >> 5, ll = l & 31;
    int hd = ll >> 2;
    float ald = aldv[node * 8 + hd];
    int beg = rowptr[node], end = rowptr[node + 1];
    float den = 0.f;
    f32x2 a0 = {0.f, 0.f}, a1 = {0.f, 0.f}, a2 = {0.f, 0.f}, a3 = {0.f, 0.f};
    const uchar_t* fb = h1 + ll * 8;
    for (int p = beg; p < end; p += 8) {
        int4 s4 = *(const int4*)(ssrc + p + half * 4);
        float e0 = als[s4.x * 8 + hd], e1 = als[s4.y * 8 + hd];
        float e2 = als[s4.z * 8 + hd], e3 = als[s4.w * 8 + hd];
        uint2 g0 = *(const uint2*)(fb + (size_t)s4.x * 256);
        uint2 g1 = *(const uint2*)(fb + (size_t)s4.y * 256);
        uint2 g2 = *(const uint2*)(fb + (size_t)s4.z * 256);
        uint2 g3 = *(const uint2*)(fb + (size_t)s4.w * 256);
        float w0 = exp2fast(lrelu(e0 + ald)), w1 = exp2fast(lrelu(e1 + ald));
        float w2 = exp2fast(lrelu(e2 + ald)), w3 = exp2fast(lrelu(e3 + ald));
        den += (w0 + w1) + (w2 + w3);
        #define DQ(g, wv) { \
            f32x2 q0 = __builtin_amdgcn_cvt_pk_f32_fp8((int)g.x, false); \
            f32x2 q1 = __builtin_amdgcn_cvt_pk_f32_fp8((int)g.x, true);  \
            f32x2 q2 = __builtin_amdgcn_cvt_pk_f32_fp8((int)g.y, false); \
            f32x2 q3 = __builtin_amdgcn_cvt_pk_f32_fp8((int)g.y, true);  \
            f32x2 w2v = {wv, wv}; \
            a0 += w2v * q0; a1 += w2v * q1; a2 += w2v * q2; a3 += w2v * q3; }
        DQ(g0, w0) DQ(g1, w1) DQ(g2, w2) DQ(g3, w3)
        #undef DQ
    }
    den += __shfl_xor(den, 32);
    a0.x += __shfl_xor(a0.x, 32); a0.y += __shfl_xor(a0.y, 32);
    a1.x += __shfl_xor(a1.x, 32); a1.y += __shfl_xor(a1.y, 32);
    a2.x += __shfl_xor(a2.x, 32); a2.y += __shfl_xor(a2.y, 32);
    a3.x += __shfl_xor(a3.x, 32); a3.y += __shfl_xor(a3.y, 32);
    if (half == 0) {
        float inv = 1.f / den;
        float4 bv0 = *(const float4*)(b1 + ll * 8);
        float4 bv1 = *(const float4*)(b1 + ll * 8 + 4);
        float v0 = a0.x * inv + bv0.x, v1 = a0.y * inv + bv0.y;
        float v2 = a1.x * inv + bv0.z, v3 = a1.y * inv + bv0.w;
        float v4 = a2.x * inv + bv1.x, v5 = a2.y * inv + bv1.y;
        float v6 = a3.x * inv + bv1.z, v7 = a3.y * inv + bv1.w;
        u16x4 o0, o1;
        o0.x = f2b((v0 > 0.f) ? v0 : __expf(v0) - 1.f);
        o0.y = f2b((v1 > 0.f) ? v1 : __expf(v1) - 1.f);
        o0.z = f2b((v2 > 0.f) ? v2 : __expf(v2) - 1.f);
        o0.w = f2b((v3 > 0.f) ? v3 : __expf(v3) - 1.f);
        o1.x = f2b((v4 > 0.f) ? v4 : __expf(v4) - 1.f);
        o1.y = f2b((v5 > 0.f) ? v5 : __expf(v5) - 1.f);
        o1.z = f2b((v6 > 0.f) ? v6 : __expf(v6) - 1.f);
        o1.w = f2b((v7 > 0.f) ? v7 : __expf(v7) - 1.f);
        ushort_t* op = hout + (size_t)node * 256 + ll * 8;
        *(u16x4*)op = o0;
        *(u16x4*)(op + 4) = o1;
    }
}

// ---------------- layer-2 aggregation: weight-lane specialization + fp8 gather ----------------
// weight role (all 64 lanes): e = l&7, hw = l>>3 -> one weight per iter.
// feature role (lanes <40): hd = l/5, cg = l%5; weights fetched via shuffle from lane hd*8+e.

__global__ void agg2_kernel(const uchar_t* __restrict__ h2, const float* __restrict__ als,
                            const float* __restrict__ aldv, const float* __restrict__ b2,
                            const int* __restrict__ rowptr, const int* __restrict__ ssrc,
                            float* __restrict__ out, int n) {
    int node = blockIdx.x * 4 + (threadIdx.x >> 6);
    if (node >= n) return;
    int l = threadIdx.x & 63;
    // weight role
    int ew = l & 7, hw = l >> 3;
    float aldw = aldv[node * 8 + hw];
    // feature role
    int li = (l < 40) ? l : 0;
    int hd = li / 5;
    int cg = li - hd * 5;
    int wbase = hd * 8;                    // lane holding (hd, e=0)
    int beg = rowptr[node], end = rowptr[node + 1];
    const uchar_t* base = h2 + hd * 40 + cg * 8;
    float wacc = 0.f;
    f32x2 acc01 = {0.f, 0.f}, acc23 = {0.f, 0.f}, acc45 = {0.f, 0.f}, acc67 = {0.f, 0.f};
    for (int p = beg; p < end; p += 8) {
        // one weight per lane (8 edges x 8 heads)
        int sw = ssrc[p + ew];
        float wv = exp2fast(lrelu(als[sw * 8 + hw] + aldw));
        wacc += wv;
        // feature gather (8 edges, this lane's 8 classes)
        int4 sA = *(const int4*)(ssrc + p);
        int4 sB = *(const int4*)(ssrc + p + 4);
        uint2 g0 = *(const uint2*)(base + (size_t)sA.x * 320);
        uint2 g1 = *(const uint2*)(base + (size_t)sA.y * 320);
        uint2 g2 = *(const uint2*)(base + (size_t)sA.z * 320);
        uint2 g3 = *(const uint2*)(base + (size_t)sA.w * 320);
        uint2 g4 = *(const uint2*)(base + (size_t)sB.x * 320);
        uint2 g5 = *(const uint2*)(base + (size_t)sB.y * 320);
        uint2 g6 = *(const uint2*)(base + (size_t)sB.z * 320);
        uint2 g7 = *(const uint2*)(base + (size_t)sB.w * 320);
        // fetch this head's 8 weights from weight lanes
        float w0 = __shfl(wv, wbase + 0), w1 = __shfl(wv, wbase + 1);
        float w2 = __shfl(wv, wbase + 2), w3 = __shfl(wv, wbase + 3);
        float w4 = __shfl(wv, wbase + 4), w5 = __shfl(wv, wbase + 5);
        float w6 = __shfl(wv, wbase + 6), w7 = __shfl(wv, wbase + 7);
        #define DQ(g, wv_) { \
            f32x2 q0 = __builtin_amdgcn_cvt_pk_f32_fp8((int)g.x, false); \
            f32x2 q1 = __builtin_amdgcn_cvt_pk_f32_fp8((int)g.x, true);  \
            f32x2 q2 = __builtin_amdgcn_cvt_pk_f32_fp8((int)g.y, false); \
            f32x2 q3 = __builtin_amdgcn_cvt_pk_f32_fp8((int)g.y, true);  \
            f32x2 w2v = {wv_, wv_}; \
            acc01 += w2v * q0; acc23 += w2v * q1; \
            acc45 += w2v * q2; acc67 += w2v * q3; }
        DQ(g0, w0) DQ(g1, w1) DQ(g2, w2) DQ(g3, w3)
        DQ(g4, w4) DQ(g5, w5) DQ(g6, w6) DQ(g7, w7)
        #undef DQ
    }
    // den per head: reduce wacc over edge slots, then fetch
    wacc += __shfl_xor(wacc, 1);
    wacc += __shfl_xor(wacc, 2);
    wacc += __shfl_xor(wacc, 4);
    float den = __shfl(wacc, wbase);
    float inv = 1.f / den;
    float v[8] = {acc01.x * inv, acc01.y * inv, acc23.x * inv, acc23.y * inv,
                  acc45.x * inv, acc45.y * inv, acc67.x * inv, acc67.y * inv};
    #pragma unroll
    for (int j = 0; j < 8; ++j) {
        float s = v[j];
        s += __shfl_down(s, 20);
        s += __shfl_down(s, 10);
        s += __shfl_down(s, 5);
        v[j] = s;
    }
    if (l < 5) {
        float wv[8];
        #pragma unroll
        for (int j = 0; j < 8; ++j) wv[j] = 0.125f * v[j] + b2[l * 8 + j];
        float m8 = wv[0];
        #pragma unroll
        for (int j = 1; j < 8; ++j) m8 = fmaxf(m8, wv[j]);
        float mx = m8;
        #pragma unroll
        for (int k = 0; k < 5; ++k) mx = fmaxf(mx, __shfl(m8, k));
        float se8 = 0.f;
        #pragma unroll
        for (int j = 0; j < 8; ++j) se8 += __expf(wv[j] - mx);
        float se = 0.f;
        #pragma unroll
        for (int k = 0; k < 5; ++k) se += __shfl(se8, k);
        float lse = mx + __logf(se);
        float* op = out + (size_t)node * 40 + l * 8;
        float4 o0 = {wv[0] - lse, wv[1] - lse, wv[2] - lse, wv[3] - lse};
        float4 o1 = {wv[4] - lse, wv[5] - lse, wv[6] - lse, wv[7] - lse};
        *(float4*)op = o0;
        *(float4*)(op + 4) = o1;
    }
}

// ---------------- launch ----------------

extern "C" void kernel_launch(void* const* d_in, const int* in_sizes, int n_in,
                              void* d_out, int out_size, void* d_ws, size_t ws_size,
                              hipStream_t stream) {
    const float* x      = (const float*)d_in[0];
    const int*   ei     = (const int*)d_in[1];
    const float* W1     = (const float*)d_in[2];
    const float* a_src1 = (const float*)d_in[3];
    const float* a_dst1 = (const float*)d_in[4];
    const float* b1     = (const float*)d_in[5];
    const float* W2     = (const float*)d_in[6];
    const float* a_src2 = (const float*)d_in[7];
    const float* a_dst2 = (const float*)d_in[8];
    const float* b2     = (const float*)d_in[9];
    float* out = (float*)d_out;

    const int n    = in_sizes[0] / 128;   // 50000
    const int E    = in_sizes[1] / 2;     // 800000
    const int Etot = E + n;
    const int EpM  = Etot + 7 * n + 16;   // upper bound on padded edge count
    const int nb   = (n + 255) / 256;     // scan blocks

    char* w = (char*)d_ws;
    auto take = [&](size_t bytes) {
        char* p = w;
        w += (bytes + 255) & ~(size_t)255;
        return p;
    };
    int*      deg    = (int*)take((size_t)n * 4);
    int*      rowptr = (int*)take((size_t)(n + 1) * 4);
    int*      cursor = (int*)take((size_t)n * 4);
    int*      bsum   = (int*)take((size_t)(nb + 1) * 4);
    int*      ssrc   = (int*)take((size_t)EpM * 4);
    ushort_t* xb     = (ushort_t*)take((size_t)n * 128 * 2);
    ushort_t* w1b    = (ushort_t*)take((size_t)272 * 128 * 2);   // 256 W1 rows + 16 wa rows
    ushort_t* w2b    = (ushort_t*)take((size_t)336 * 256 * 2);   // 320 W2 rows + 16 wa rows
    uchar_t*  h1f8   = (uchar_t*)take((size_t)(n + 1) * 256);
    ushort_t* helu   = (ushort_t*)take((size_t)n * 256 * 2);
    uchar_t*  h2f8   = (uchar_t*)take((size_t)(n + 1) * 320);
    float*    als1   = (float*)take((size_t)(n + 1) * 8 * 4);
    float*    ald1   = (float*)take((size_t)n * 8 * 4);
    float*    als2   = (float*)take((size_t)(n + 1) * 8 * 4);
    float*    ald2   = (float*)take((size_t)n * 8 * 4);

    // merged prologue (W converts + wa folds + sentinel pads + deg zero)
    prep_kernel<<<65 + nb, 256, 0, stream>>>(W1, W2, a_src1, a_dst1, a_src2, a_dst2,
                                             w1b, w2b, als1, als2, h1f8, h2f8, deg, n);

    // merged x-convert + degree count, then CSR (3-phase parallel scan, sentinel prefill)
    int eb = (Etot + 255) / 256;
    convx_count_kernel<<<2048 + eb, 256, 0, stream>>>(x, xb, n * 128 / 4, ei, E, n, deg);
    scan_part_kernel<<<nb, 256, 0, stream>>>(deg, bsum, n);
    scan_top_kernel<<<1, 256, 0, stream>>>(bsum, nb);
    scan_write_kernel<<<nb, 256, 0, stream>>>(deg, bsum, rowptr, cursor, ssrc, n);
    scatter_kernel<<<eb, 256, 0, stream>>>(ei, E, n, cursor, ssrc);

    int gb = (n + 127) / 128;
    int nb4 = (n + 3) / 4;

    // layer 1 (gemm computes fp8 h1 AND f32 als1/ald1)
    gemm_lds_al<17, 128><<<gb, 512, 0, stream>>>(xb, w1b, h1f8, als1, ald1, n);
    agg1_kernel<<<nb4, 256, 0, stream>>>(h1f8, als1, ald1, b1, rowptr, ssrc, helu, n);

    // layer 2
    gemm_lds_al<21, 256><<<gb, 512, 0, stream>>>(helu, w2b, h2f8, als2, ald2, n);
    agg2_kernel<<<nb4, 256, 0, stream>>>(h2f8, als2, ald2, b2, rowptr, ssrc, out, n);
}